// Round 1
// baseline (3916.116 us; speedup 1.0000x reference)
//
#include <hip/hip_runtime.h>
#include <math.h>

#define N_TOT   4096
#define N_SRC   2048
#define DIMF    256
#define NCLASS  31
#define LAMBDA  0.01f

// median target ranks (0-indexed) among 4192256 non-NaN values
#define K_MED1  2096127LL
#define K_MED2  2096128LL

// ---- ws layout (bytes) ----
#define WS_ACC    0           // 2 doubles
#define WS_HIST0  64          // 4096 u32
#define WS_HISTA  16448       // 4096 u32
#define WS_HISTB  32832       // 4096 u32
#define WS_H2A    49216       // 256 u32
#define WS_H2B    50240       // 256 u32
#define WS_STATE  51264       // 64 u32
#define WS_CNT    51520       // 64 u32
#define WS_CNT2   51776       // 64 u32
#define WS_BSTART 52032       // 64 u32
#define WS_META   52288       // 128 i32: ncls[32], m0c[32], cstart[32], blkoff[32]
#define WS_SCAL   52800       // 16 f32: [0]=sigma, [1]=gamma0, [2]=gamma1
#define ZERO_BYTES 53248
#define WS_PERM   53248       // 4096 i32
#define WS_XN     69632       // 4096 f32
#define WS_DS     1048576     // 2048*2048 f32 (16.78 MB)
#define WS_KBLK   17825792    // class K blocks (8 MB budget)

// solver capacity (binomial(4096,1/62): mean 66, sd 8 -> MAXM=112 is +5.7 sigma)
#define MAXM 112
#define MAXN 256
#define HST  113
#define NSLOT 25   // ceil(112*113/2 / 256)

// ---------------- reductions ----------------
__device__ __forceinline__ double blockReduceSum(double v, double* red) {
#pragma unroll
  for (int o = 32; o > 0; o >>= 1) v += __shfl_down(v, o, 64);
  int w = threadIdx.x >> 6, lane = threadIdx.x & 63;
  __syncthreads();
  if (lane == 0) red[w] = v;
  __syncthreads();
  return red[0] + red[1] + red[2] + red[3];
}

__device__ __forceinline__ double blockReduceMax(double v, double* red) {
#pragma unroll
  for (int o = 32; o > 0; o >>= 1) { double u = __shfl_down(v, o, 64); v = fmax(v, u); }
  int w = threadIdx.x >> 6, lane = threadIdx.x & 63;
  __syncthreads();
  if (lane == 0) red[4 + w] = v;
  __syncthreads();
  return fmax(fmax(red[4], red[5]), fmax(red[6], red[7]));
}

// ---------------- row norms ----------------
__global__ __launch_bounds__(256) void xn_kernel(const float* __restrict__ sf,
                                                 const float* __restrict__ tf,
                                                 float* __restrict__ xn) {
  int wid = threadIdx.x >> 6, lane = threadIdx.x & 63;
  int row = blockIdx.x * 4 + wid;
  const float* src = (row < N_SRC) ? (sf + (size_t)row * DIMF) : (tf + (size_t)(row - N_SRC) * DIMF);
  float4 v = ((const float4*)src)[lane];
  float s = v.x * v.x + v.y * v.y + v.z * v.z + v.w * v.w;
#pragma unroll
  for (int o = 32; o > 0; o >>= 1) s += __shfl_down(s, o, 64);
  if (lane == 0) xn[row] = s;
}

// ---------------- source pairwise sq-dists (for median) ----------------
__global__ __launch_bounds__(256) void dist_k(const float* __restrict__ sf,
                                              const float* __restrict__ xn,
                                              float* __restrict__ Ds) {
  __shared__ float As[16][68];
  __shared__ float Bs[16][68];
  const int tx = threadIdx.x, ty = threadIdx.y;
  const int tid = ty * 16 + tx;
  const int R = blockIdx.y * 64, C = blockIdx.x * 64;
  float acc[4][4] = {};
  for (int kc = 0; kc < 256; kc += 16) {
    int i = tid >> 2, q = tid & 3;
    float4 va = ((const float4*)(sf + (size_t)(R + i) * 256 + kc))[q];
    As[q * 4 + 0][i] = va.x; As[q * 4 + 1][i] = va.y; As[q * 4 + 2][i] = va.z; As[q * 4 + 3][i] = va.w;
    float4 vb = ((const float4*)(sf + (size_t)(C + i) * 256 + kc))[q];
    Bs[q * 4 + 0][i] = vb.x; Bs[q * 4 + 1][i] = vb.y; Bs[q * 4 + 2][i] = vb.z; Bs[q * 4 + 3][i] = vb.w;
    __syncthreads();
#pragma unroll
    for (int k = 0; k < 16; k++) {
      float4 a = *(const float4*)&As[k][ty * 4];
      float4 b = *(const float4*)&Bs[k][tx * 4];
      acc[0][0] += a.x * b.x; acc[0][1] += a.x * b.y; acc[0][2] += a.x * b.z; acc[0][3] += a.x * b.w;
      acc[1][0] += a.y * b.x; acc[1][1] += a.y * b.y; acc[1][2] += a.y * b.z; acc[1][3] += a.y * b.w;
      acc[2][0] += a.z * b.x; acc[2][1] += a.z * b.y; acc[2][2] += a.z * b.z; acc[2][3] += a.z * b.w;
      acc[3][0] += a.w * b.x; acc[3][1] += a.w * b.y; acc[3][2] += a.w * b.z; acc[3][3] += a.w * b.w;
    }
    __syncthreads();
  }
  const float INF = __int_as_float(0x7f800000);
  int jbase = C + tx * 4;
  float xnj0 = xn[jbase + 0], xnj1 = xn[jbase + 1], xnj2 = xn[jbase + 2], xnj3 = xn[jbase + 3];
#pragma unroll
  for (int r = 0; r < 4; r++) {
    int i = R + ty * 4 + r;
    float xni = xn[i];
    float4 o;
    o.x = fmaxf(xni + xnj0 - 2.f * acc[r][0], 0.f);
    o.y = fmaxf(xni + xnj1 - 2.f * acc[r][1], 0.f);
    o.z = fmaxf(xni + xnj2 - 2.f * acc[r][2], 0.f);
    o.w = fmaxf(xni + xnj3 - 2.f * acc[r][3], 0.f);
    if (i == jbase + 0) o.x = INF;
    if (i == jbase + 1) o.y = INF;
    if (i == jbase + 2) o.z = INF;
    if (i == jbase + 3) o.w = INF;
    ((float4*)&Ds[(size_t)i * 2048 + jbase])[0] = o;
  }
}

// ---------------- radix-select median (3 passes) ----------------
__global__ __launch_bounds__(256) void hist0_k(const float* __restrict__ Ds, unsigned* __restrict__ h) {
  __shared__ unsigned lh[4096];
  for (int i = threadIdx.x; i < 4096; i += 256) lh[i] = 0;
  __syncthreads();
  unsigned total = 2048u * 2048u;
  for (unsigned idx = blockIdx.x * 256 + threadIdx.x; idx < total; idx += gridDim.x * 256) {
    unsigned u = __float_as_uint(Ds[idx]);
    atomicAdd(&lh[u >> 20], 1u);
  }
  __syncthreads();
  for (int i = threadIdx.x; i < 4096; i += 256) if (lh[i]) atomicAdd(&h[i], lh[i]);
}

__global__ __launch_bounds__(256) void hist1_k(const float* __restrict__ Ds, const unsigned* __restrict__ st,
                                               unsigned* __restrict__ hA, unsigned* __restrict__ hB) {
  __shared__ unsigned lA[4096];
  __shared__ unsigned lB[4096];
  for (int i = threadIdx.x; i < 4096; i += 256) { lA[i] = 0; lB[i] = 0; }
  __syncthreads();
  unsigned s0 = st[0], s1 = st[2];
  unsigned total = 2048u * 2048u;
  for (unsigned idx = blockIdx.x * 256 + threadIdx.x; idx < total; idx += gridDim.x * 256) {
    unsigned u = __float_as_uint(Ds[idx]);
    unsigned hi = u >> 20, mid = (u >> 8) & 0xFFFu;
    if (hi == s0) atomicAdd(&lA[mid], 1u);
    if (hi == s1) atomicAdd(&lB[mid], 1u);
  }
  __syncthreads();
  for (int i = threadIdx.x; i < 4096; i += 256) {
    if (lA[i]) atomicAdd(&hA[i], lA[i]);
    if (lB[i]) atomicAdd(&hB[i], lB[i]);
  }
}

__global__ __launch_bounds__(256) void hist2_k(const float* __restrict__ Ds, const unsigned* __restrict__ st,
                                               unsigned* __restrict__ hA, unsigned* __restrict__ hB) {
  __shared__ unsigned lA[256];
  __shared__ unsigned lB[256];
  if (threadIdx.x < 256) { lA[threadIdx.x] = 0; lB[threadIdx.x] = 0; }
  __syncthreads();
  unsigned p0 = (st[0] << 12) | st[4];
  unsigned p1 = (st[2] << 12) | st[6];
  unsigned total = 2048u * 2048u;
  for (unsigned idx = blockIdx.x * 256 + threadIdx.x; idx < total; idx += gridDim.x * 256) {
    unsigned u = __float_as_uint(Ds[idx]);
    unsigned pre = u >> 8;
    if (pre == p0) atomicAdd(&lA[u & 0xFFu], 1u);
    if (pre == p1) atomicAdd(&lB[u & 0xFFu], 1u);
  }
  __syncthreads();
  if (lA[threadIdx.x]) atomicAdd(&hA[threadIdx.x], lA[threadIdx.x]);
  if (lB[threadIdx.x]) atomicAdd(&hB[threadIdx.x], lB[threadIdx.x]);
}

__device__ void scan_find(const unsigned* hist, int nbins, long long k, unsigned* shOut) {
  __shared__ long long tsum[256];
  int per = nbins / 256;
  long long s = 0;
  for (int q = 0; q < per; q++) s += hist[threadIdx.x * per + q];
  tsum[threadIdx.x] = s;
  __syncthreads();
  if (threadIdx.x == 0) {
    long long run = 0;
    for (int t = 0; t < 256; t++) { long long v = tsum[t]; tsum[t] = run; run += v; }
  }
  __syncthreads();
  long long run = tsum[threadIdx.x];
  for (int q = 0; q < per; q++) {
    unsigned c = hist[threadIdx.x * per + q];
    if (k >= run && k < run + (long long)c) { shOut[0] = (unsigned)(threadIdx.x * per + q); shOut[1] = (unsigned)(k - run); }
    run += c;
  }
  __syncthreads();
}

__global__ __launch_bounds__(256) void scan0_k(const unsigned* __restrict__ h, unsigned* __restrict__ st) {
  __shared__ unsigned r0[2];
  __shared__ unsigned r1[2];
  scan_find(h, 4096, K_MED1, r0);
  scan_find(h, 4096, K_MED2, r1);
  if (threadIdx.x == 0) { st[0] = r0[0]; st[1] = r0[1]; st[2] = r1[0]; st[3] = r1[1]; }
}

__global__ __launch_bounds__(256) void scan1_k(const unsigned* __restrict__ hA, const unsigned* __restrict__ hB,
                                               unsigned* __restrict__ st) {
  __shared__ unsigned r0[2];
  __shared__ unsigned r1[2];
  long long kA = (long long)st[1];
  long long kB = (long long)st[3];
  scan_find(hA, 4096, kA, r0);
  scan_find(hB, 4096, kB, r1);
  if (threadIdx.x == 0) { st[4] = r0[0]; st[5] = r0[1]; st[6] = r1[0]; st[7] = r1[1]; }
}

__global__ __launch_bounds__(256) void scan2_k(const unsigned* __restrict__ hA, const unsigned* __restrict__ hB,
                                               unsigned* __restrict__ st, float* __restrict__ scal) {
  __shared__ unsigned r0[2];
  __shared__ unsigned r1[2];
  long long kA = (long long)st[5];
  long long kB = (long long)st[7];
  scan_find(hA, 256, kA, r0);
  scan_find(hB, 256, kB, r1);
  if (threadIdx.x == 0) {
    unsigned v1 = (st[0] << 20) | (st[4] << 8) | r0[0];
    unsigned v2 = (st[2] << 20) | (st[6] << 8) | r1[0];
    scal[0] = 0.5f * (__uint_as_float(v1) + __uint_as_float(v2));  // sigma
  }
}

// ---------------- class/domain bucketing ----------------
__global__ void cnt_k(const int* __restrict__ y, const int* __restrict__ l, unsigned* __restrict__ cnt) {
  int i = blockIdx.x * 256 + threadIdx.x;
  if (i < N_TOT) atomicAdd(&cnt[y[i] * 2 + l[i]], 1u);
}

__global__ void scank_k(const unsigned* __restrict__ cnt, unsigned* __restrict__ bstart,
                        int* __restrict__ meta, float* __restrict__ scal) {
  unsigned run = 0;
  for (int b = 0; b < 62; b++) { bstart[b] = run; run += cnt[b]; }
  int* ncls = meta; int* m0c = meta + 32; int* cstart = meta + 64; int* blkoff = meta + 96;
  unsigned run2 = 0, cnt0 = 0;
  for (int c = 0; c < NCLASS; c++) {
    int n = (int)(cnt[2 * c] + cnt[2 * c + 1]);
    ncls[c] = n; m0c[c] = (int)cnt[2 * c]; cstart[c] = (int)bstart[2 * c];
    blkoff[c] = (int)run2; run2 += (unsigned)(n * n);
    cnt0 += cnt[2 * c];
  }
  scal[1] = (float)((double)cnt0 / (4096.0 * 4096.0));
  scal[2] = (float)((double)(N_TOT - cnt0) / (4096.0 * 4096.0));
}

__global__ void scat_k(const int* __restrict__ y, const int* __restrict__ l,
                       const unsigned* __restrict__ bstart, unsigned* __restrict__ cnt2,
                       int* __restrict__ perm) {
  int i = blockIdx.x * 256 + threadIdx.x;
  if (i < N_TOT) {
    int b = y[i] * 2 + l[i];
    unsigned pos = bstart[b] + atomicAdd(&cnt2[b], 1u);
    perm[pos] = i;
  }
}

// ---------------- build per-class K blocks ----------------
__global__ __launch_bounds__(256) void build_k(const float* __restrict__ sf, const float* __restrict__ tf,
                                               const float* __restrict__ xn, const int* __restrict__ perm,
                                               const int* __restrict__ meta, const float* __restrict__ scal,
                                               float* __restrict__ gK) {
  const int c = blockIdx.z;
  const int n = meta[c];
  const int cs = meta[64 + c];
  const int bo = meta[96 + c];
  const int tx = threadIdx.x, ty = threadIdx.y;
  const int i0 = blockIdx.y * 16, j0 = blockIdx.x * 16;
  if (i0 >= n || j0 >= n) return;
  __shared__ float As[16][260];
  __shared__ float Bs[16][260];
  __shared__ int ra[16];
  __shared__ int rb[16];
  int tid = ty * 16 + tx;
  if (tid < 16) { int il = i0 + tid; ra[tid] = (il < n) ? perm[cs + il] : -1; }
  else if (tid < 32) { int jl = j0 + tid - 16; rb[tid - 16] = (jl < n) ? perm[cs + jl] : -1; }
  __syncthreads();
  for (int e = tid; e < 1024; e += 256) {
    int r = e >> 6, q = e & 63;
    int g = ra[r];
    if (g >= 0) {
      const float* src = (g < N_SRC) ? (sf + (size_t)g * DIMF) : (tf + (size_t)(g - N_SRC) * DIMF);
      ((float4*)&As[r][q * 4])[0] = ((const float4*)src)[q];
    }
    int g2 = rb[r];
    if (g2 >= 0) {
      const float* src = (g2 < N_SRC) ? (sf + (size_t)g2 * DIMF) : (tf + (size_t)(g2 - N_SRC) * DIMF);
      ((float4*)&Bs[r][q * 4])[0] = ((const float4*)src)[q];
    }
  }
  __syncthreads();
  int il = i0 + ty, jl = j0 + tx;
  if (il < n && jl < n) {
    float dot = 0.f;
    const float4* a4 = (const float4*)&As[ty][0];
    const float4* b4 = (const float4*)&Bs[tx][0];
#pragma unroll 16
    for (int q = 0; q < 64; q++) {
      float4 a = a4[q], b = b4[q];
      dot += a.x * b.x + a.y * b.y + a.z * b.z + a.w * b.w;
    }
    int gi = ra[ty], gj = rb[tx];
    float d = xn[gi] + xn[gj] - 2.f * dot;
    gK[(size_t)bo + (size_t)il * n + jl] = expf(-d / scal[0]);
  }
}

// ---------------- per-(class,domain) damped Newton ----------------
__global__ __launch_bounds__(256) void solver_k(const float* __restrict__ gK, const int* __restrict__ meta,
                                                const float* __restrict__ scal, double* __restrict__ acc) {
  const int c = blockIdx.x >> 1, d = blockIdx.x & 1;
  const int n = meta[c];
  const int m0 = meta[32 + c];
  const int m = d ? (n - m0) : m0;
  const int c0 = d ? m0 : 0;
  const int bo = meta[96 + c];
  const float gamma = scal[1 + d];
  const int tid = threadIdx.x;

  __shared__ float H[MAXM * HST];
  __shared__ float Av[MAXN];
  __shared__ float Bv[MAXN];
  __shared__ float Sv[MAXN];
  __shared__ float bc[MAXM];
  __shared__ float th[MAXM];
  __shared__ float gv[MAXM];
  __shared__ float pv[MAXM];
  __shared__ float idd[MAXM];
  __shared__ float rowb[8][MAXM + 1];
  __shared__ double red[9];

  const float* K = gK + bo;
  const int st = n;
  const int P = m * (m + 1) / 2;

  // packed lower-tri (j>=k) slot indices, fixed per thread
  int ejk[NSLOT];
#pragma unroll
  for (int s2 = 0; s2 < NSLOT; s2++) {
    int e = tid + (s2 << 8);
    int j = (int)((sqrtf(8.f * (float)e + 1.f) - 1.f) * 0.5f);
    while ((j + 1) * (j + 2) / 2 <= e) ++j;
    while (j * (j + 1) / 2 > e) --j;
    ejk[s2] = (j << 16) | (e - j * (j + 1) / 2);
  }

  // b_j = (1/N) * sum over same-domain rows of K; theta = 0
  for (int j = tid; j < m; j += 256) {
    float sum = 0.f;
    for (int r = 0; r < m; r++) sum += K[(c0 + r) * st + c0 + j];
    bc[j] = sum * (1.0f / 4096.0f);
    th[j] = 0.f;
  }
  __syncthreads();

  for (int it = 0; it < 14; it++) {
    // A_i = sum_j th_j K[(c0+j)*st + i]   (uses K symmetry for coalescing)
    for (int i = tid; i < n; i += 256) {
      float a = 0.f;
      for (int j = 0; j < m; j++) a += th[j] * K[(c0 + j) * st + i];
      Av[i] = a;
    }
    __syncthreads();
    // S, obj
    double o = 0.0;
    for (int i = tid; i < n; i += 256) {
      float si = gamma * expf(fminf(Av[i] - 1.f, 30.f));
      Sv[i] = si; o += (double)si;
    }
    for (int j = tid; j < m; j += 256) {
      float t_ = th[j];
      o += (double)(-bc[j] * t_ + LAMBDA * t_ * t_);
    }
    double obj = blockReduceSum(o, red);
    // g_j
    for (int j = tid; j < m; j += 256) {
      float s_ = 0.f;
      for (int i = 0; i < n; i++) s_ += K[i * st + c0 + j] * Sv[i];
      gv[j] = s_ - bc[j] + 2.f * LAMBDA * th[j];
    }
    __syncthreads();
    // H = K~^T diag(S) K~ + 2*lambda*I  (packed tri in registers, staged rows)
    float hacc[NSLOT];
#pragma unroll
    for (int s2 = 0; s2 < NSLOT; s2++) hacc[s2] = 0.f;
    for (int ib = 0; ib < n; ib += 8) {
      int nr = min(8, n - ib);
      for (int ii = 0; ii < nr; ii++)
        for (int j = tid; j < m; j += 256)
          rowb[ii][j] = K[(ib + ii) * st + c0 + j];
      __syncthreads();
      for (int ii = 0; ii < nr; ii++) {
        float sfac = Sv[ib + ii];
#pragma unroll
        for (int s2 = 0; s2 < NSLOT; s2++) {
          int e = tid + (s2 << 8);
          if (e < P) {
            int j = ejk[s2] >> 16, k = ejk[s2] & 0xffff;
            hacc[s2] += sfac * rowb[ii][j] * rowb[ii][k];
          }
        }
      }
      __syncthreads();
    }
#pragma unroll
    for (int s2 = 0; s2 < NSLOT; s2++) {
      int e = tid + (s2 << 8);
      if (e < P) { int j = ejk[s2] >> 16, k = ejk[s2] & 0xffff; H[j * HST + k] = hacc[s2]; }
    }
    __syncthreads();
    for (int j = tid; j < m; j += 256) H[j * HST + j] += 2.f * LAMBDA;
    __syncthreads();
    // LDL^T factor (columns kept unscaled; D on diagonal)
    for (int kk = 0; kk < m - 1; kk++) {
      float iv = 1.f / H[kk * HST + kk];
      int j = kk + 1 + tid;
      if (j < m) {
        float f = H[j * HST + kk] * iv;
        for (int l = kk + 1; l <= j; l++) H[j * HST + l] -= f * H[l * HST + kk];
      }
      __syncthreads();
    }
    for (int j = tid; j < m; j += 256) idd[j] = 1.f / H[j * HST + j];
    __syncthreads();
    // solve H p = -g
    for (int j = tid; j < m; j += 256) pv[j] = -gv[j];
    __syncthreads();
    for (int kk = 0; kk < m - 1; kk++) {
      float zk = pv[kk] * idd[kk];
      int j = kk + 1 + tid;
      if (j < m) pv[j] -= H[j * HST + kk] * zk;
      __syncthreads();
    }
    for (int j = tid; j < m; j += 256) pv[j] *= idd[j];
    __syncthreads();
    for (int kk = m - 1; kk >= 1; kk--) {
      float pk = pv[kk];
      if (tid < kk) pv[tid] -= H[kk * HST + tid] * idd[tid] * pk;
      __syncthreads();
    }
    // B = K~ p ; gtp ; pmax
    for (int i = tid; i < n; i += 256) {
      float bsum = 0.f;
      for (int j = 0; j < m; j++) bsum += pv[j] * K[(c0 + j) * st + i];
      Bv[i] = bsum;
    }
    double gtp_l = 0.0, pmax_l = 0.0;
    for (int j = tid; j < m; j += 256) {
      gtp_l += (double)gv[j] * (double)pv[j];
      double ap = fabs((double)pv[j]); if (ap > pmax_l) pmax_l = ap;
    }
    double gtp = blockReduceSum(gtp_l, red);
    double pmax = blockReduceMax(pmax_l, red);
    float t = 1.f;
    if (!(gtp < 0.0)) {
      t = 0.f;  // not a descent direction (numerical / converged): stop
    } else {
      for (int ls = 0; ls < 12; ls++) {
        double ol = 0.0;
        for (int i = tid; i < n; i += 256)
          ol += (double)(gamma * expf(fminf(Av[i] + t * Bv[i] - 1.f, 30.f)));
        for (int j = tid; j < m; j += 256) {
          float tj = th[j] + t * pv[j];
          ol += (double)(-bc[j] * tj + LAMBDA * tj * tj);
        }
        double ot = blockReduceSum(ol, red);
        if (ot <= obj + 1e-4 * (double)t * gtp) break;
        t *= 0.5f;
      }
    }
    for (int j = tid; j < m; j += 256) th[j] += t * pv[j];
    __syncthreads();
    if ((double)t * pmax < 1e-8) break;
  }

  // final contributions with converged theta
  for (int i = tid; i < n; i += 256) {
    float a = 0.f;
    for (int j = 0; j < m; j++) a += th[j] * K[(c0 + j) * st + i];
    Av[i] = a;
  }
  __syncthreads();
  double t2l = 0.0;
  for (int i = tid; i < n; i += 256) t2l += (double)(gamma * expf(fminf(Av[i] - 1.f, 30.f)));
  double t1l = 0.0;
  for (int j = tid; j < m; j += 256) t1l += (double)(bc[j] * th[j]);
  double t1 = blockReduceSum(t1l, red);
  double t2 = blockReduceSum(t2l, red);
  if (tid == 0) {
    atomicAdd(&acc[0], t1);
    atomicAdd(&acc[1], t2);
  }
}

__global__ void final_k(const double* __restrict__ acc, float* __restrict__ out) {
  out[0] = (float)(acc[0] - acc[1]);
}

// ---------------- launcher ----------------
extern "C" void kernel_launch(void* const* d_in, const int* in_sizes, int n_in,
                              void* d_out, int out_size, void* d_ws, size_t ws_size,
                              hipStream_t stream) {
  const float* sf = (const float*)d_in[0];
  const float* tf = (const float*)d_in[1];
  const int* y = (const int*)d_in[2];
  const int* l = (const int*)d_in[3];
  char* ws = (char*)d_ws;

  double*   acc    = (double*)(ws + WS_ACC);
  unsigned* hist0  = (unsigned*)(ws + WS_HIST0);
  unsigned* histA  = (unsigned*)(ws + WS_HISTA);
  unsigned* histB  = (unsigned*)(ws + WS_HISTB);
  unsigned* h2A    = (unsigned*)(ws + WS_H2A);
  unsigned* h2B    = (unsigned*)(ws + WS_H2B);
  unsigned* state  = (unsigned*)(ws + WS_STATE);
  unsigned* cnt    = (unsigned*)(ws + WS_CNT);
  unsigned* cnt2   = (unsigned*)(ws + WS_CNT2);
  unsigned* bstart = (unsigned*)(ws + WS_BSTART);
  int*      meta   = (int*)(ws + WS_META);
  float*    scal   = (float*)(ws + WS_SCAL);
  int*      perm   = (int*)(ws + WS_PERM);
  float*    xnp    = (float*)(ws + WS_XN);
  float*    Ds     = (float*)(ws + WS_DS);
  float*    gK     = (float*)(ws + WS_KBLK);

  hipMemsetAsync(d_ws, 0, ZERO_BYTES, stream);
  hipLaunchKernelGGL(xn_kernel, dim3(1024), dim3(256), 0, stream, sf, tf, xnp);
  hipLaunchKernelGGL(dist_k, dim3(32, 32), dim3(16, 16), 0, stream, sf, xnp, Ds);
  hipLaunchKernelGGL(hist0_k, dim3(512), dim3(256), 0, stream, Ds, hist0);
  hipLaunchKernelGGL(scan0_k, dim3(1), dim3(256), 0, stream, hist0, state);
  hipLaunchKernelGGL(hist1_k, dim3(512), dim3(256), 0, stream, Ds, state, histA, histB);
  hipLaunchKernelGGL(scan1_k, dim3(1), dim3(256), 0, stream, histA, histB, state);
  hipLaunchKernelGGL(hist2_k, dim3(512), dim3(256), 0, stream, Ds, state, h2A, h2B);
  hipLaunchKernelGGL(scan2_k, dim3(1), dim3(256), 0, stream, h2A, h2B, state, scal);
  hipLaunchKernelGGL(cnt_k, dim3(16), dim3(256), 0, stream, y, l, cnt);
  hipLaunchKernelGGL(scank_k, dim3(1), dim3(1), 0, stream, cnt, bstart, meta, scal);
  hipLaunchKernelGGL(scat_k, dim3(16), dim3(256), 0, stream, y, l, bstart, cnt2, perm);
  hipLaunchKernelGGL(build_k, dim3(16, 16, NCLASS), dim3(16, 16), 0, stream, sf, tf, xnp, perm, meta, scal, gK);
  hipLaunchKernelGGL(solver_k, dim3(62), dim3(256), 0, stream, gK, meta, scal, acc);
  hipLaunchKernelGGL(final_k, dim3(1), dim3(1), 0, stream, acc, (float*)d_out);
}

// Round 2
// 2009.166 us; speedup vs baseline: 1.9491x; 1.9491x over previous
//
#include <hip/hip_runtime.h>
#include <math.h>

#define N_TOT   4096
#define N_SRC   2048
#define DIMF    256
#define NCLASS  31
#define LAMBDA  0.01f

// median target ranks (0-indexed) among 4192256 non-NaN values
#define K_MED1  2096127LL
#define K_MED2  2096128LL

// ---- ws layout (bytes) ----
#define WS_ACC    0           // 2 doubles
#define WS_HIST0  64          // 4096 u32
#define WS_HISTA  16448       // 4096 u32
#define WS_HISTB  32832       // 4096 u32
#define WS_H2A    49216       // 256 u32
#define WS_H2B    50240       // 256 u32
#define WS_STATE  51264       // 64 u32
#define WS_CNT    51520       // 64 u32
#define WS_CNT2   51776       // 64 u32
#define WS_BSTART 52032       // 64 u32
#define WS_META   52288       // 128 i32: ncls[32], m0c[32], cstart[32], blkoff[32]
#define WS_SCAL   52800       // 16 f32: [0]=sigma, [1]=gamma0, [2]=gamma1
#define ZERO_BYTES 53248
#define WS_PERM   53248       // 4096 i32
#define WS_XN     69632       // 4096 f32
#define WS_DS     1048576     // 2048*2048 f32 (16.78 MB)
#define WS_KBLK   17825792    // class K blocks (8 MB budget)

// solver capacity (binomial(4096,1/62): mean 66, sd 8 -> MAXM=112 is +5.7 sigma)
#define MAXM 112
#define MAXN 256
#define HST  113
#define NSLOT 25   // ceil(112*113/2 / 256)  -- element slots (factor)
#define MT   28    // ceil(MAXM/4)
#define NTILE 2    // ceil(MT*(MT+1)/2 / 256) = ceil(406/256)
#define RST  116   // rowb stride (mult of 4 for float4)

// ---------------- reductions ----------------
__device__ __forceinline__ double blockReduceSum(double v, double* red) {
#pragma unroll
  for (int o = 32; o > 0; o >>= 1) v += __shfl_down(v, o, 64);
  int w = threadIdx.x >> 6, lane = threadIdx.x & 63;
  __syncthreads();
  if (lane == 0) red[w] = v;
  __syncthreads();
  return red[0] + red[1] + red[2] + red[3];
}

__device__ __forceinline__ double blockReduceMax(double v, double* red) {
#pragma unroll
  for (int o = 32; o > 0; o >>= 1) { double u = __shfl_down(v, o, 64); v = fmax(v, u); }
  int w = threadIdx.x >> 6, lane = threadIdx.x & 63;
  __syncthreads();
  if (lane == 0) red[4 + w] = v;
  __syncthreads();
  return fmax(fmax(red[4], red[5]), fmax(red[6], red[7]));
}

// ---------------- row norms ----------------
__global__ __launch_bounds__(256) void xn_kernel(const float* __restrict__ sf,
                                                 const float* __restrict__ tf,
                                                 float* __restrict__ xn) {
  int wid = threadIdx.x >> 6, lane = threadIdx.x & 63;
  int row = blockIdx.x * 4 + wid;
  const float* src = (row < N_SRC) ? (sf + (size_t)row * DIMF) : (tf + (size_t)(row - N_SRC) * DIMF);
  float4 v = ((const float4*)src)[lane];
  float s = v.x * v.x + v.y * v.y + v.z * v.z + v.w * v.w;
#pragma unroll
  for (int o = 32; o > 0; o >>= 1) s += __shfl_down(s, o, 64);
  if (lane == 0) xn[row] = s;
}

// ---------------- source pairwise sq-dists (for median) ----------------
__global__ __launch_bounds__(256) void dist_k(const float* __restrict__ sf,
                                              const float* __restrict__ xn,
                                              float* __restrict__ Ds) {
  __shared__ float As[16][68];
  __shared__ float Bs[16][68];
  const int tx = threadIdx.x, ty = threadIdx.y;
  const int tid = ty * 16 + tx;
  const int R = blockIdx.y * 64, C = blockIdx.x * 64;
  float acc[4][4] = {};
  for (int kc = 0; kc < 256; kc += 16) {
    int i = tid >> 2, q = tid & 3;
    float4 va = ((const float4*)(sf + (size_t)(R + i) * 256 + kc))[q];
    As[q * 4 + 0][i] = va.x; As[q * 4 + 1][i] = va.y; As[q * 4 + 2][i] = va.z; As[q * 4 + 3][i] = va.w;
    float4 vb = ((const float4*)(sf + (size_t)(C + i) * 256 + kc))[q];
    Bs[q * 4 + 0][i] = vb.x; Bs[q * 4 + 1][i] = vb.y; Bs[q * 4 + 2][i] = vb.z; Bs[q * 4 + 3][i] = vb.w;
    __syncthreads();
#pragma unroll
    for (int k = 0; k < 16; k++) {
      float4 a = *(const float4*)&As[k][ty * 4];
      float4 b = *(const float4*)&Bs[k][tx * 4];
      acc[0][0] += a.x * b.x; acc[0][1] += a.x * b.y; acc[0][2] += a.x * b.z; acc[0][3] += a.x * b.w;
      acc[1][0] += a.y * b.x; acc[1][1] += a.y * b.y; acc[1][2] += a.y * b.z; acc[1][3] += a.y * b.w;
      acc[2][0] += a.z * b.x; acc[2][1] += a.z * b.y; acc[2][2] += a.z * b.z; acc[2][3] += a.z * b.w;
      acc[3][0] += a.w * b.x; acc[3][1] += a.w * b.y; acc[3][2] += a.w * b.z; acc[3][3] += a.w * b.w;
    }
    __syncthreads();
  }
  const float INF = __int_as_float(0x7f800000);
  int jbase = C + tx * 4;
  float xnj0 = xn[jbase + 0], xnj1 = xn[jbase + 1], xnj2 = xn[jbase + 2], xnj3 = xn[jbase + 3];
#pragma unroll
  for (int r = 0; r < 4; r++) {
    int i = R + ty * 4 + r;
    float xni = xn[i];
    float4 o;
    o.x = fmaxf(xni + xnj0 - 2.f * acc[r][0], 0.f);
    o.y = fmaxf(xni + xnj1 - 2.f * acc[r][1], 0.f);
    o.z = fmaxf(xni + xnj2 - 2.f * acc[r][2], 0.f);
    o.w = fmaxf(xni + xnj3 - 2.f * acc[r][3], 0.f);
    if (i == jbase + 0) o.x = INF;
    if (i == jbase + 1) o.y = INF;
    if (i == jbase + 2) o.z = INF;
    if (i == jbase + 3) o.w = INF;
    ((float4*)&Ds[(size_t)i * 2048 + jbase])[0] = o;
  }
}

// ---------------- radix-select median (3 passes) ----------------
__global__ __launch_bounds__(256) void hist0_k(const float* __restrict__ Ds, unsigned* __restrict__ h) {
  __shared__ unsigned lh[4096];
  for (int i = threadIdx.x; i < 4096; i += 256) lh[i] = 0;
  __syncthreads();
  unsigned total = 2048u * 2048u;
  for (unsigned idx = blockIdx.x * 256 + threadIdx.x; idx < total; idx += gridDim.x * 256) {
    unsigned u = __float_as_uint(Ds[idx]);
    atomicAdd(&lh[u >> 20], 1u);
  }
  __syncthreads();
  for (int i = threadIdx.x; i < 4096; i += 256) if (lh[i]) atomicAdd(&h[i], lh[i]);
}

__global__ __launch_bounds__(256) void hist1_k(const float* __restrict__ Ds, const unsigned* __restrict__ st,
                                               unsigned* __restrict__ hA, unsigned* __restrict__ hB) {
  __shared__ unsigned lA[4096];
  __shared__ unsigned lB[4096];
  for (int i = threadIdx.x; i < 4096; i += 256) { lA[i] = 0; lB[i] = 0; }
  __syncthreads();
  unsigned s0 = st[0], s1 = st[2];
  unsigned total = 2048u * 2048u;
  for (unsigned idx = blockIdx.x * 256 + threadIdx.x; idx < total; idx += gridDim.x * 256) {
    unsigned u = __float_as_uint(Ds[idx]);
    unsigned hi = u >> 20, mid = (u >> 8) & 0xFFFu;
    if (hi == s0) atomicAdd(&lA[mid], 1u);
    if (hi == s1) atomicAdd(&lB[mid], 1u);
  }
  __syncthreads();
  for (int i = threadIdx.x; i < 4096; i += 256) {
    if (lA[i]) atomicAdd(&hA[i], lA[i]);
    if (lB[i]) atomicAdd(&hB[i], lB[i]);
  }
}

__global__ __launch_bounds__(256) void hist2_k(const float* __restrict__ Ds, const unsigned* __restrict__ st,
                                               unsigned* __restrict__ hA, unsigned* __restrict__ hB) {
  __shared__ unsigned lA[256];
  __shared__ unsigned lB[256];
  if (threadIdx.x < 256) { lA[threadIdx.x] = 0; lB[threadIdx.x] = 0; }
  __syncthreads();
  unsigned p0 = (st[0] << 12) | st[4];
  unsigned p1 = (st[2] << 12) | st[6];
  unsigned total = 2048u * 2048u;
  for (unsigned idx = blockIdx.x * 256 + threadIdx.x; idx < total; idx += gridDim.x * 256) {
    unsigned u = __float_as_uint(Ds[idx]);
    unsigned pre = u >> 8;
    if (pre == p0) atomicAdd(&lA[u & 0xFFu], 1u);
    if (pre == p1) atomicAdd(&lB[u & 0xFFu], 1u);
  }
  __syncthreads();
  if (lA[threadIdx.x]) atomicAdd(&hA[threadIdx.x], lA[threadIdx.x]);
  if (lB[threadIdx.x]) atomicAdd(&hB[threadIdx.x], lB[threadIdx.x]);
}

__device__ void scan_find(const unsigned* hist, int nbins, long long k, unsigned* shOut) {
  __shared__ long long tsum[256];
  int per = nbins / 256;
  long long s = 0;
  for (int q = 0; q < per; q++) s += hist[threadIdx.x * per + q];
  tsum[threadIdx.x] = s;
  __syncthreads();
  if (threadIdx.x == 0) {
    long long run = 0;
    for (int t = 0; t < 256; t++) { long long v = tsum[t]; tsum[t] = run; run += v; }
  }
  __syncthreads();
  long long run = tsum[threadIdx.x];
  for (int q = 0; q < per; q++) {
    unsigned c = hist[threadIdx.x * per + q];
    if (k >= run && k < run + (long long)c) { shOut[0] = (unsigned)(threadIdx.x * per + q); shOut[1] = (unsigned)(k - run); }
    run += c;
  }
  __syncthreads();
}

__global__ __launch_bounds__(256) void scan0_k(const unsigned* __restrict__ h, unsigned* __restrict__ st) {
  __shared__ unsigned r0[2];
  __shared__ unsigned r1[2];
  scan_find(h, 4096, K_MED1, r0);
  scan_find(h, 4096, K_MED2, r1);
  if (threadIdx.x == 0) { st[0] = r0[0]; st[1] = r0[1]; st[2] = r1[0]; st[3] = r1[1]; }
}

__global__ __launch_bounds__(256) void scan1_k(const unsigned* __restrict__ hA, const unsigned* __restrict__ hB,
                                               unsigned* __restrict__ st) {
  __shared__ unsigned r0[2];
  __shared__ unsigned r1[2];
  long long kA = (long long)st[1];
  long long kB = (long long)st[3];
  scan_find(hA, 4096, kA, r0);
  scan_find(hB, 4096, kB, r1);
  if (threadIdx.x == 0) { st[4] = r0[0]; st[5] = r0[1]; st[6] = r1[0]; st[7] = r1[1]; }
}

__global__ __launch_bounds__(256) void scan2_k(const unsigned* __restrict__ hA, const unsigned* __restrict__ hB,
                                               unsigned* __restrict__ st, float* __restrict__ scal) {
  __shared__ unsigned r0[2];
  __shared__ unsigned r1[2];
  long long kA = (long long)st[5];
  long long kB = (long long)st[7];
  scan_find(hA, 256, kA, r0);
  scan_find(hB, 256, kB, r1);
  if (threadIdx.x == 0) {
    unsigned v1 = (st[0] << 20) | (st[4] << 8) | r0[0];
    unsigned v2 = (st[2] << 20) | (st[6] << 8) | r1[0];
    scal[0] = 0.5f * (__uint_as_float(v1) + __uint_as_float(v2));  // sigma
  }
}

// ---------------- class/domain bucketing ----------------
__global__ void cnt_k(const int* __restrict__ y, const int* __restrict__ l, unsigned* __restrict__ cnt) {
  int i = blockIdx.x * 256 + threadIdx.x;
  if (i < N_TOT) atomicAdd(&cnt[y[i] * 2 + l[i]], 1u);
}

__global__ void scank_k(const unsigned* __restrict__ cnt, unsigned* __restrict__ bstart,
                        int* __restrict__ meta, float* __restrict__ scal) {
  unsigned run = 0;
  for (int b = 0; b < 62; b++) { bstart[b] = run; run += cnt[b]; }
  int* ncls = meta; int* m0c = meta + 32; int* cstart = meta + 64; int* blkoff = meta + 96;
  unsigned run2 = 0, cnt0 = 0;
  for (int c = 0; c < NCLASS; c++) {
    int n = (int)(cnt[2 * c] + cnt[2 * c + 1]);
    ncls[c] = n; m0c[c] = (int)cnt[2 * c]; cstart[c] = (int)bstart[2 * c];
    blkoff[c] = (int)run2; run2 += (unsigned)(n * n);
    cnt0 += cnt[2 * c];
  }
  scal[1] = (float)((double)cnt0 / (4096.0 * 4096.0));
  scal[2] = (float)((double)(N_TOT - cnt0) / (4096.0 * 4096.0));
}

__global__ void scat_k(const int* __restrict__ y, const int* __restrict__ l,
                       const unsigned* __restrict__ bstart, unsigned* __restrict__ cnt2,
                       int* __restrict__ perm) {
  int i = blockIdx.x * 256 + threadIdx.x;
  if (i < N_TOT) {
    int b = y[i] * 2 + l[i];
    unsigned pos = bstart[b] + atomicAdd(&cnt2[b], 1u);
    perm[pos] = i;
  }
}

// ---------------- build per-class K blocks ----------------
__global__ __launch_bounds__(256) void build_k(const float* __restrict__ sf, const float* __restrict__ tf,
                                               const float* __restrict__ xn, const int* __restrict__ perm,
                                               const int* __restrict__ meta, const float* __restrict__ scal,
                                               float* __restrict__ gK) {
  const int c = blockIdx.z;
  const int n = meta[c];
  const int cs = meta[64 + c];
  const int bo = meta[96 + c];
  const int tx = threadIdx.x, ty = threadIdx.y;
  const int i0 = blockIdx.y * 16, j0 = blockIdx.x * 16;
  if (i0 >= n || j0 >= n) return;
  __shared__ float As[16][260];
  __shared__ float Bs[16][260];
  __shared__ int ra[16];
  __shared__ int rb[16];
  int tid = ty * 16 + tx;
  if (tid < 16) { int il = i0 + tid; ra[tid] = (il < n) ? perm[cs + il] : -1; }
  else if (tid < 32) { int jl = j0 + tid - 16; rb[tid - 16] = (jl < n) ? perm[cs + jl] : -1; }
  __syncthreads();
  for (int e = tid; e < 1024; e += 256) {
    int r = e >> 6, q = e & 63;
    int g = ra[r];
    if (g >= 0) {
      const float* src = (g < N_SRC) ? (sf + (size_t)g * DIMF) : (tf + (size_t)(g - N_SRC) * DIMF);
      ((float4*)&As[r][q * 4])[0] = ((const float4*)src)[q];
    }
    int g2 = rb[r];
    if (g2 >= 0) {
      const float* src = (g2 < N_SRC) ? (sf + (size_t)g2 * DIMF) : (tf + (size_t)(g2 - N_SRC) * DIMF);
      ((float4*)&Bs[r][q * 4])[0] = ((const float4*)src)[q];
    }
  }
  __syncthreads();
  int il = i0 + ty, jl = j0 + tx;
  if (il < n && jl < n) {
    float dot = 0.f;
    const float4* a4 = (const float4*)&As[ty][0];
    const float4* b4 = (const float4*)&Bs[tx][0];
#pragma unroll 16
    for (int q = 0; q < 64; q++) {
      float4 a = a4[q], b = b4[q];
      dot += a.x * b.x + a.y * b.y + a.z * b.z + a.w * b.w;
    }
    int gi = ra[ty], gj = rb[tx];
    float d = xn[gi] + xn[gj] - 2.f * dot;
    gK[(size_t)bo + (size_t)il * n + jl] = expf(-d / scal[0]);
  }
}

// ---------------- per-(class,domain) damped Newton ----------------
// R2 rewrite: parallel right-looking LDL^T (depth m barriers, not m^2/2 serial
// LDS ops), 4x4-register-tiled H build with float4 LDS reads and sqrt(S)
// pre-scaled rows, early exit on ||g||_inf before the heavy phase.
__global__ __launch_bounds__(256) void solver_k(const float* __restrict__ gK, const int* __restrict__ meta,
                                                const float* __restrict__ scal, double* __restrict__ acc) {
  const int c = blockIdx.x >> 1, d = blockIdx.x & 1;
  const int n = meta[c];
  const int m0 = meta[32 + c];
  const int m = d ? (n - m0) : m0;
  const int c0 = d ? m0 : 0;
  const int bo = meta[96 + c];
  const float gamma = scal[1 + d];
  const int tid = threadIdx.x;

  __shared__ float H[MAXM * HST];      // 50624 B
  __shared__ float rowb[8][RST];       // 3712 B
  __shared__ float Av[MAXN];
  __shared__ float Bv[MAXN];
  __shared__ float Sv[MAXN];
  __shared__ float sqS[MAXN];
  __shared__ float bc[MAXM];
  __shared__ float th[MAXM];
  __shared__ float gv[MAXM];
  __shared__ float pv[MAXM];
  __shared__ float idd[MAXM];
  __shared__ double red[9];

  const float* K = gK + bo;
  const int st = n;
  const int P = m * (m + 1) / 2;
  const int mt = (m + 3) >> 2;
  const int mp4 = mt << 2;
  const int Pt = mt * (mt + 1) / 2;

  // packed lower-tri (j>=k) element slots for the factor
  int ejk[NSLOT];
#pragma unroll
  for (int s2 = 0; s2 < NSLOT; s2++) {
    int e = tid + (s2 << 8);
    int j = (int)((sqrtf(8.f * (float)e + 1.f) - 1.f) * 0.5f);
    while ((j + 1) * (j + 2) / 2 <= e) ++j;
    while (j * (j + 1) / 2 > e) --j;
    ejk[s2] = (j << 16) | (e - j * (j + 1) / 2);
  }
  // 4x4 tile slots for the H build (quad-triangle)
  int tji[NTILE];
#pragma unroll
  for (int s2 = 0; s2 < NTILE; s2++) {
    int t = tid + (s2 << 8);
    int ja = (int)((sqrtf(8.f * (float)t + 1.f) - 1.f) * 0.5f);
    while ((ja + 1) * (ja + 2) / 2 <= t) ++ja;
    while (ja * (ja + 1) / 2 > t) --ja;
    tji[s2] = (ja << 8) | (t - ja * (ja + 1) / 2);
  }

  // b_j = (1/N) * sum over same-domain rows of K; theta = 0
  for (int j = tid; j < m; j += 256) {
    float sum = 0.f;
    const float* Kj = K + (size_t)c0 * st + c0 + j;
    for (int r = 0; r < m; r++) sum += Kj[(size_t)r * st];
    bc[j] = sum * (1.0f / 4096.0f);
    th[j] = 0.f;
  }
  __syncthreads();

  bool done = false;
  for (int it = 0; it < 25; it++) {
    // ---- A_i = sum_j th_j K[(c0+j)*st + i]  (coalesced over i) ----
    for (int i = tid; i < n; i += 256) {
      const float* Kc = K + (size_t)c0 * st + i;
      float a = 0.f;
      int j = 0;
      for (; j + 3 < m; j += 4)
        a += th[j] * Kc[(size_t)j * st] + th[j + 1] * Kc[(size_t)(j + 1) * st]
           + th[j + 2] * Kc[(size_t)(j + 2) * st] + th[j + 3] * Kc[(size_t)(j + 3) * st];
      for (; j < m; j++) a += th[j] * Kc[(size_t)j * st];
      Av[i] = a;
    }
    __syncthreads();
    // ---- S, sqrt(S), obj ----
    double o = 0.0;
    for (int i = tid; i < n; i += 256) {
      float si = gamma * expf(fminf(Av[i] - 1.f, 30.f));
      Sv[i] = si; sqS[i] = sqrtf(si); o += (double)si;
    }
    for (int j = tid; j < m; j += 256) {
      float t_ = th[j];
      o += (double)(-bc[j] * t_ + LAMBDA * t_ * t_);
    }
    double obj = blockReduceSum(o, red);
    // ---- gradient + inf-norm ----
    double gm = 0.0;
    for (int j = tid; j < m; j += 256) {
      const float* Kj = K + c0 + j;
      float s_ = 0.f;
      int i = 0;
      for (; i + 3 < n; i += 4)
        s_ += Kj[(size_t)i * st] * Sv[i] + Kj[(size_t)(i + 1) * st] * Sv[i + 1]
            + Kj[(size_t)(i + 2) * st] * Sv[i + 2] + Kj[(size_t)(i + 3) * st] * Sv[i + 3];
      for (; i < n; i++) s_ += Kj[(size_t)i * st] * Sv[i];
      float g = s_ - bc[j] + 2.f * LAMBDA * th[j];
      gv[j] = g;
      double ag = fabs((double)g); if (ag > gm) gm = ag;
    }
    double gmax = blockReduceMax(gm, red);
    if (gmax < 1e-7) { done = true; break; }   // Av/Sv valid for current th

    // ---- H = W^T W + 2*lambda*I, W = diag(sqrt(S)) K~; 4x4 reg tiles ----
    float hc[NTILE * 16];
#pragma unroll
    for (int q = 0; q < NTILE * 16; q++) hc[q] = 0.f;
    for (int ib = 0; ib < n; ib += 8) {
      int nr = min(8, n - ib);
      for (int ii = 0; ii < nr; ii++) {
        float sq = sqS[ib + ii];
        for (int j = tid; j < mp4; j += 256)
          rowb[ii][j] = (j < m) ? K[(size_t)(ib + ii) * st + c0 + j] * sq : 0.f;
      }
      __syncthreads();
      for (int ii = 0; ii < nr; ii++) {
#pragma unroll
        for (int s2 = 0; s2 < NTILE; s2++) {
          if (tid + (s2 << 8) < Pt) {
            int ja = tji[s2] >> 8, ka = tji[s2] & 255;
            float4 wj = *(const float4*)&rowb[ii][4 * ja];
            float4 wk = *(const float4*)&rowb[ii][4 * ka];
            float* h = hc + s2 * 16;
            h[0]  += wj.x * wk.x; h[1]  += wj.x * wk.y; h[2]  += wj.x * wk.z; h[3]  += wj.x * wk.w;
            h[4]  += wj.y * wk.x; h[5]  += wj.y * wk.y; h[6]  += wj.y * wk.z; h[7]  += wj.y * wk.w;
            h[8]  += wj.z * wk.x; h[9]  += wj.z * wk.y; h[10] += wj.z * wk.z; h[11] += wj.z * wk.w;
            h[12] += wj.w * wk.x; h[13] += wj.w * wk.y; h[14] += wj.w * wk.z; h[15] += wj.w * wk.w;
          }
        }
      }
      __syncthreads();
    }
#pragma unroll
    for (int s2 = 0; s2 < NTILE; s2++) {
      int t = tid + (s2 << 8);
      if (t < Pt) {
        int ja = tji[s2] >> 8, ka = tji[s2] & 255;
#pragma unroll
        for (int a = 0; a < 4; a++) {
          int j = 4 * ja + a;
          if (j < m) {
#pragma unroll
            for (int b = 0; b < 4; b++) {
              int k = 4 * ka + b;
              if (k <= j) H[j * HST + k] = hc[s2 * 16 + a * 4 + b];
            }
          }
        }
      }
    }
    __syncthreads();
    for (int j = tid; j < m; j += 256) H[j * HST + j] += 2.f * LAMBDA;
    __syncthreads();

    // ---- parallel right-looking LDL^T (unscaled columns; D on diag) ----
    for (int kk = 0; kk < m - 1; kk++) {
      float iv = 1.f / H[kk * HST + kk];
#pragma unroll
      for (int s2 = 0; s2 < NSLOT; s2++) {
        int e = tid + (s2 << 8);
        if (e < P) {
          int j = ejk[s2] >> 16, k = ejk[s2] & 0xffff;
          if (k > kk) H[j * HST + k] -= H[j * HST + kk] * iv * H[k * HST + kk];
        }
      }
      __syncthreads();
    }
    for (int j = tid; j < m; j += 256) idd[j] = 1.f / H[j * HST + j];
    __syncthreads();
    // ---- solve H p = -g ----
    for (int j = tid; j < m; j += 256) pv[j] = -gv[j];
    __syncthreads();
    for (int kk = 0; kk < m - 1; kk++) {
      float zk = pv[kk] * idd[kk];
      int j = kk + 1 + tid;
      if (j < m) pv[j] -= H[j * HST + kk] * zk;
      __syncthreads();
    }
    for (int j = tid; j < m; j += 256) pv[j] *= idd[j];
    __syncthreads();
    for (int kk = m - 1; kk >= 1; kk--) {
      float pk = pv[kk];
      if (tid < kk) pv[tid] -= H[kk * HST + tid] * idd[tid] * pk;
      __syncthreads();
    }
    // ---- B = K~ p ; gtp ----
    for (int i = tid; i < n; i += 256) {
      const float* Kc = K + (size_t)c0 * st + i;
      float bsum = 0.f;
      int j = 0;
      for (; j + 3 < m; j += 4)
        bsum += pv[j] * Kc[(size_t)j * st] + pv[j + 1] * Kc[(size_t)(j + 1) * st]
              + pv[j + 2] * Kc[(size_t)(j + 2) * st] + pv[j + 3] * Kc[(size_t)(j + 3) * st];
      for (; j < m; j++) bsum += pv[j] * Kc[(size_t)j * st];
      Bv[i] = bsum;
    }
    double gtp_l = 0.0;
    for (int j = tid; j < m; j += 256) gtp_l += (double)gv[j] * (double)pv[j];
    double gtp = blockReduceSum(gtp_l, red);
    if (!(gtp < 0.0)) { done = true; break; }  // numerically converged; Av/Sv valid
    // ---- Armijo line search ----
    float t = 1.f;
    for (int ls = 0; ls < 10; ls++) {
      double ol = 0.0;
      for (int i = tid; i < n; i += 256)
        ol += (double)(gamma * expf(fminf(Av[i] + t * Bv[i] - 1.f, 30.f)));
      for (int j = tid; j < m; j += 256) {
        float tj = th[j] + t * pv[j];
        ol += (double)(-bc[j] * tj + LAMBDA * tj * tj);
      }
      double ot = blockReduceSum(ol, red);
      if (ot <= obj + 1e-4 * (double)t * gtp) break;
      t *= 0.5f;
    }
    for (int j = tid; j < m; j += 256) th[j] += t * pv[j];
    __syncthreads();
  }

  if (!done) {
    // recompute Av/Sv for the final theta (iteration cap path)
    for (int i = tid; i < n; i += 256) {
      const float* Kc = K + (size_t)c0 * st + i;
      float a = 0.f;
      for (int j = 0; j < m; j++) a += th[j] * Kc[(size_t)j * st];
      Av[i] = a;
    }
    __syncthreads();
    for (int i = tid; i < n; i += 256) Sv[i] = gamma * expf(fminf(Av[i] - 1.f, 30.f));
  }
  double t1l = 0.0, t2l = 0.0;
  for (int i = tid; i < n; i += 256) t2l += (double)Sv[i];
  for (int j = tid; j < m; j += 256) t1l += (double)(bc[j] * th[j]);
  double t1 = blockReduceSum(t1l, red);
  double t2 = blockReduceSum(t2l, red);
  if (tid == 0) {
    atomicAdd(&acc[0], t1);
    atomicAdd(&acc[1], t2);
  }
}

__global__ void final_k(const double* __restrict__ acc, float* __restrict__ out) {
  out[0] = (float)(acc[0] - acc[1]);
}

// ---------------- launcher ----------------
extern "C" void kernel_launch(void* const* d_in, const int* in_sizes, int n_in,
                              void* d_out, int out_size, void* d_ws, size_t ws_size,
                              hipStream_t stream) {
  const float* sf = (const float*)d_in[0];
  const float* tf = (const float*)d_in[1];
  const int* y = (const int*)d_in[2];
  const int* l = (const int*)d_in[3];
  char* ws = (char*)d_ws;

  double*   acc    = (double*)(ws + WS_ACC);
  unsigned* hist0  = (unsigned*)(ws + WS_HIST0);
  unsigned* histA  = (unsigned*)(ws + WS_HISTA);
  unsigned* histB  = (unsigned*)(ws + WS_HISTB);
  unsigned* h2A    = (unsigned*)(ws + WS_H2A);
  unsigned* h2B    = (unsigned*)(ws + WS_H2B);
  unsigned* state  = (unsigned*)(ws + WS_STATE);
  unsigned* cnt    = (unsigned*)(ws + WS_CNT);
  unsigned* cnt2   = (unsigned*)(ws + WS_CNT2);
  unsigned* bstart = (unsigned*)(ws + WS_BSTART);
  int*      meta   = (int*)(ws + WS_META);
  float*    scal   = (float*)(ws + WS_SCAL);
  int*      perm   = (int*)(ws + WS_PERM);
  float*    xnp    = (float*)(ws + WS_XN);
  float*    Ds     = (float*)(ws + WS_DS);
  float*    gK     = (float*)(ws + WS_KBLK);

  hipMemsetAsync(d_ws, 0, ZERO_BYTES, stream);
  hipLaunchKernelGGL(xn_kernel, dim3(1024), dim3(256), 0, stream, sf, tf, xnp);
  hipLaunchKernelGGL(dist_k, dim3(32, 32), dim3(16, 16), 0, stream, sf, xnp, Ds);
  hipLaunchKernelGGL(hist0_k, dim3(512), dim3(256), 0, stream, Ds, hist0);
  hipLaunchKernelGGL(scan0_k, dim3(1), dim3(256), 0, stream, hist0, state);
  hipLaunchKernelGGL(hist1_k, dim3(512), dim3(256), 0, stream, Ds, state, histA, histB);
  hipLaunchKernelGGL(scan1_k, dim3(1), dim3(256), 0, stream, histA, histB, state);
  hipLaunchKernelGGL(hist2_k, dim3(512), dim3(256), 0, stream, Ds, state, h2A, h2B);
  hipLaunchKernelGGL(scan2_k, dim3(1), dim3(256), 0, stream, h2A, h2B, state, scal);
  hipLaunchKernelGGL(cnt_k, dim3(16), dim3(256), 0, stream, y, l, cnt);
  hipLaunchKernelGGL(scank_k, dim3(1), dim3(1), 0, stream, cnt, bstart, meta, scal);
  hipLaunchKernelGGL(scat_k, dim3(16), dim3(256), 0, stream, y, l, bstart, cnt2, perm);
  hipLaunchKernelGGL(build_k, dim3(16, 16, NCLASS), dim3(16, 16), 0, stream, sf, tf, xnp, perm, meta, scal, gK);
  hipLaunchKernelGGL(solver_k, dim3(62), dim3(256), 0, stream, gK, meta, scal, acc);
  hipLaunchKernelGGL(final_k, dim3(1), dim3(1), 0, stream, acc, (float*)d_out);
}

// Round 3
// 956.731 us; speedup vs baseline: 4.0932x; 2.1000x over previous
//
#include <hip/hip_runtime.h>
#include <math.h>

#define N_TOT   4096
#define N_SRC   2048
#define DIMF    256
#define NCLASS  31
#define LAMBDA  0.01f

// median target ranks (0-indexed) among 4192256 non-NaN values
#define K_MED1  2096127LL
#define K_MED2  2096128LL

// ---- ws layout (bytes) ----
#define WS_ACC    0           // 2 doubles
#define WS_HIST0  64          // 4096 u32
#define WS_HISTA  16448       // 4096 u32
#define WS_HISTB  32832       // 4096 u32
#define WS_H2A    49216       // 256 u32
#define WS_H2B    50240       // 256 u32
#define WS_STATE  51264       // 64 u32
#define WS_CNT    51520       // 64 u32
#define WS_CNT2   51776       // 64 u32
#define WS_BSTART 52032       // 64 u32
#define WS_META   52288       // 128 i32: ncls[32], m0c[32], cstart[32], blkoff[32]
#define WS_SCAL   52800       // 16 f32: [0]=sigma, [1]=gamma0, [2]=gamma1
#define ZERO_BYTES 53248
#define WS_PERM   53248       // 4096 i32
#define WS_XN     69632       // 4096 f32
#define WS_DS     1048576     // 2048*2048 f32 (16.78 MB)
#define WS_KBLK   17825792    // class K blocks (8 MB budget)

// solver capacity (binomial(4096,1/62): mean 66, sd 8 -> MAXM=112 is +5.7 sigma)
#define MAXM 112
#define MAXN 256
#define HST  113
#define NSLOT 25   // ceil(112*113/2 / 256)  -- element slots (factor)
#define NTILE 2    // ceil(ceil(112/4)*(..+1)/2 / 256)
#define RST  116   // rowb stride

// ---------------- reductions ----------------
__device__ __forceinline__ double blockReduceSum(double v, double* red) {
#pragma unroll
  for (int o = 32; o > 0; o >>= 1) v += __shfl_down(v, o, 64);
  int w = threadIdx.x >> 6, lane = threadIdx.x & 63;
  __syncthreads();
  if (lane == 0) red[w] = v;
  __syncthreads();
  return red[0] + red[1] + red[2] + red[3];
}

__device__ __forceinline__ void blockReduceSumMax(double s, double mx, double* red,
                                                  double& os, double& om) {
#pragma unroll
  for (int o = 32; o > 0; o >>= 1) {
    s += __shfl_down(s, o, 64);
    double u = __shfl_down(mx, o, 64);
    mx = fmax(mx, u);
  }
  int w = threadIdx.x >> 6, lane = threadIdx.x & 63;
  __syncthreads();
  if (lane == 0) { red[w] = s; red[4 + w] = mx; }
  __syncthreads();
  os = red[0] + red[1] + red[2] + red[3];
  om = fmax(fmax(red[4], red[5]), fmax(red[6], red[7]));
}

// ---------------- row norms ----------------
__global__ __launch_bounds__(256) void xn_kernel(const float* __restrict__ sf,
                                                 const float* __restrict__ tf,
                                                 float* __restrict__ xn) {
  int wid = threadIdx.x >> 6, lane = threadIdx.x & 63;
  int row = blockIdx.x * 4 + wid;
  const float* src = (row < N_SRC) ? (sf + (size_t)row * DIMF) : (tf + (size_t)(row - N_SRC) * DIMF);
  float4 v = ((const float4*)src)[lane];
  float s = v.x * v.x + v.y * v.y + v.z * v.z + v.w * v.w;
#pragma unroll
  for (int o = 32; o > 0; o >>= 1) s += __shfl_down(s, o, 64);
  if (lane == 0) xn[row] = s;
}

// ---------------- source pairwise sq-dists (for median) ----------------
__global__ __launch_bounds__(256) void dist_k(const float* __restrict__ sf,
                                              const float* __restrict__ xn,
                                              float* __restrict__ Ds) {
  __shared__ float As[16][68];
  __shared__ float Bs[16][68];
  const int tx = threadIdx.x, ty = threadIdx.y;
  const int tid = ty * 16 + tx;
  const int R = blockIdx.y * 64, C = blockIdx.x * 64;
  float acc[4][4] = {};
  for (int kc = 0; kc < 256; kc += 16) {
    int i = tid >> 2, q = tid & 3;
    float4 va = ((const float4*)(sf + (size_t)(R + i) * 256 + kc))[q];
    As[q * 4 + 0][i] = va.x; As[q * 4 + 1][i] = va.y; As[q * 4 + 2][i] = va.z; As[q * 4 + 3][i] = va.w;
    float4 vb = ((const float4*)(sf + (size_t)(C + i) * 256 + kc))[q];
    Bs[q * 4 + 0][i] = vb.x; Bs[q * 4 + 1][i] = vb.y; Bs[q * 4 + 2][i] = vb.z; Bs[q * 4 + 3][i] = vb.w;
    __syncthreads();
#pragma unroll
    for (int k = 0; k < 16; k++) {
      float4 a = *(const float4*)&As[k][ty * 4];
      float4 b = *(const float4*)&Bs[k][tx * 4];
      acc[0][0] += a.x * b.x; acc[0][1] += a.x * b.y; acc[0][2] += a.x * b.z; acc[0][3] += a.x * b.w;
      acc[1][0] += a.y * b.x; acc[1][1] += a.y * b.y; acc[1][2] += a.y * b.z; acc[1][3] += a.y * b.w;
      acc[2][0] += a.z * b.x; acc[2][1] += a.z * b.y; acc[2][2] += a.z * b.z; acc[2][3] += a.z * b.w;
      acc[3][0] += a.w * b.x; acc[3][1] += a.w * b.y; acc[3][2] += a.w * b.z; acc[3][3] += a.w * b.w;
    }
    __syncthreads();
  }
  const float INF = __int_as_float(0x7f800000);
  int jbase = C + tx * 4;
  float xnj0 = xn[jbase + 0], xnj1 = xn[jbase + 1], xnj2 = xn[jbase + 2], xnj3 = xn[jbase + 3];
#pragma unroll
  for (int r = 0; r < 4; r++) {
    int i = R + ty * 4 + r;
    float xni = xn[i];
    float4 o;
    o.x = fmaxf(xni + xnj0 - 2.f * acc[r][0], 0.f);
    o.y = fmaxf(xni + xnj1 - 2.f * acc[r][1], 0.f);
    o.z = fmaxf(xni + xnj2 - 2.f * acc[r][2], 0.f);
    o.w = fmaxf(xni + xnj3 - 2.f * acc[r][3], 0.f);
    if (i == jbase + 0) o.x = INF;
    if (i == jbase + 1) o.y = INF;
    if (i == jbase + 2) o.z = INF;
    if (i == jbase + 3) o.w = INF;
    ((float4*)&Ds[(size_t)i * 2048 + jbase])[0] = o;
  }
}

// ---------------- radix-select median (3 passes) ----------------
__global__ __launch_bounds__(256) void hist0_k(const float* __restrict__ Ds, unsigned* __restrict__ h) {
  __shared__ unsigned lh[4096];
  for (int i = threadIdx.x; i < 4096; i += 256) lh[i] = 0;
  __syncthreads();
  unsigned total = 2048u * 2048u;
  for (unsigned idx = blockIdx.x * 256 + threadIdx.x; idx < total; idx += gridDim.x * 256) {
    unsigned u = __float_as_uint(Ds[idx]);
    atomicAdd(&lh[u >> 20], 1u);
  }
  __syncthreads();
  for (int i = threadIdx.x; i < 4096; i += 256) if (lh[i]) atomicAdd(&h[i], lh[i]);
}

__global__ __launch_bounds__(256) void hist1_k(const float* __restrict__ Ds, const unsigned* __restrict__ st,
                                               unsigned* __restrict__ hA, unsigned* __restrict__ hB) {
  __shared__ unsigned lA[4096];
  __shared__ unsigned lB[4096];
  for (int i = threadIdx.x; i < 4096; i += 256) { lA[i] = 0; lB[i] = 0; }
  __syncthreads();
  unsigned s0 = st[0], s1 = st[2];
  unsigned total = 2048u * 2048u;
  for (unsigned idx = blockIdx.x * 256 + threadIdx.x; idx < total; idx += gridDim.x * 256) {
    unsigned u = __float_as_uint(Ds[idx]);
    unsigned hi = u >> 20, mid = (u >> 8) & 0xFFFu;
    if (hi == s0) atomicAdd(&lA[mid], 1u);
    if (hi == s1) atomicAdd(&lB[mid], 1u);
  }
  __syncthreads();
  for (int i = threadIdx.x; i < 4096; i += 256) {
    if (lA[i]) atomicAdd(&hA[i], lA[i]);
    if (lB[i]) atomicAdd(&hB[i], lB[i]);
  }
}

__global__ __launch_bounds__(256) void hist2_k(const float* __restrict__ Ds, const unsigned* __restrict__ st,
                                               unsigned* __restrict__ hA, unsigned* __restrict__ hB) {
  __shared__ unsigned lA[256];
  __shared__ unsigned lB[256];
  if (threadIdx.x < 256) { lA[threadIdx.x] = 0; lB[threadIdx.x] = 0; }
  __syncthreads();
  unsigned p0 = (st[0] << 12) | st[4];
  unsigned p1 = (st[2] << 12) | st[6];
  unsigned total = 2048u * 2048u;
  for (unsigned idx = blockIdx.x * 256 + threadIdx.x; idx < total; idx += gridDim.x * 256) {
    unsigned u = __float_as_uint(Ds[idx]);
    unsigned pre = u >> 8;
    if (pre == p0) atomicAdd(&lA[u & 0xFFu], 1u);
    if (pre == p1) atomicAdd(&lB[u & 0xFFu], 1u);
  }
  __syncthreads();
  if (lA[threadIdx.x]) atomicAdd(&hA[threadIdx.x], lA[threadIdx.x]);
  if (lB[threadIdx.x]) atomicAdd(&hB[threadIdx.x], lB[threadIdx.x]);
}

__device__ void scan_find(const unsigned* hist, int nbins, long long k, unsigned* shOut) {
  __shared__ long long tsum[256];
  int per = nbins / 256;
  long long s = 0;
  for (int q = 0; q < per; q++) s += hist[threadIdx.x * per + q];
  tsum[threadIdx.x] = s;
  __syncthreads();
  if (threadIdx.x == 0) {
    long long run = 0;
    for (int t = 0; t < 256; t++) { long long v = tsum[t]; tsum[t] = run; run += v; }
  }
  __syncthreads();
  long long run = tsum[threadIdx.x];
  for (int q = 0; q < per; q++) {
    unsigned c = hist[threadIdx.x * per + q];
    if (k >= run && k < run + (long long)c) { shOut[0] = (unsigned)(threadIdx.x * per + q); shOut[1] = (unsigned)(k - run); }
    run += c;
  }
  __syncthreads();
}

__global__ __launch_bounds__(256) void scan0_k(const unsigned* __restrict__ h, unsigned* __restrict__ st) {
  __shared__ unsigned r0[2];
  __shared__ unsigned r1[2];
  scan_find(h, 4096, K_MED1, r0);
  scan_find(h, 4096, K_MED2, r1);
  if (threadIdx.x == 0) { st[0] = r0[0]; st[1] = r0[1]; st[2] = r1[0]; st[3] = r1[1]; }
}

__global__ __launch_bounds__(256) void scan1_k(const unsigned* __restrict__ hA, const unsigned* __restrict__ hB,
                                               unsigned* __restrict__ st) {
  __shared__ unsigned r0[2];
  __shared__ unsigned r1[2];
  long long kA = (long long)st[1];
  long long kB = (long long)st[3];
  scan_find(hA, 4096, kA, r0);
  scan_find(hB, 4096, kB, r1);
  if (threadIdx.x == 0) { st[4] = r0[0]; st[5] = r0[1]; st[6] = r1[0]; st[7] = r1[1]; }
}

__global__ __launch_bounds__(256) void scan2_k(const unsigned* __restrict__ hA, const unsigned* __restrict__ hB,
                                               unsigned* __restrict__ st, float* __restrict__ scal) {
  __shared__ unsigned r0[2];
  __shared__ unsigned r1[2];
  long long kA = (long long)st[5];
  long long kB = (long long)st[7];
  scan_find(hA, 256, kA, r0);
  scan_find(hB, 256, kB, r1);
  if (threadIdx.x == 0) {
    unsigned v1 = (st[0] << 20) | (st[4] << 8) | r0[0];
    unsigned v2 = (st[2] << 20) | (st[6] << 8) | r1[0];
    scal[0] = 0.5f * (__uint_as_float(v1) + __uint_as_float(v2));  // sigma
  }
}

// ---------------- class/domain bucketing ----------------
__global__ void cnt_k(const int* __restrict__ y, const int* __restrict__ l, unsigned* __restrict__ cnt) {
  int i = blockIdx.x * 256 + threadIdx.x;
  if (i < N_TOT) atomicAdd(&cnt[y[i] * 2 + l[i]], 1u);
}

__global__ void scank_k(const unsigned* __restrict__ cnt, unsigned* __restrict__ bstart,
                        int* __restrict__ meta, float* __restrict__ scal) {
  unsigned run = 0;
  for (int b = 0; b < 62; b++) { bstart[b] = run; run += cnt[b]; }
  int* ncls = meta; int* m0c = meta + 32; int* cstart = meta + 64; int* blkoff = meta + 96;
  unsigned run2 = 0, cnt0 = 0;
  for (int c = 0; c < NCLASS; c++) {
    int n = (int)(cnt[2 * c] + cnt[2 * c + 1]);
    ncls[c] = n; m0c[c] = (int)cnt[2 * c]; cstart[c] = (int)bstart[2 * c];
    blkoff[c] = (int)run2; run2 += (unsigned)(n * n);
    cnt0 += cnt[2 * c];
  }
  scal[1] = (float)((double)cnt0 / (4096.0 * 4096.0));
  scal[2] = (float)((double)(N_TOT - cnt0) / (4096.0 * 4096.0));
}

__global__ void scat_k(const int* __restrict__ y, const int* __restrict__ l,
                       const unsigned* __restrict__ bstart, unsigned* __restrict__ cnt2,
                       int* __restrict__ perm) {
  int i = blockIdx.x * 256 + threadIdx.x;
  if (i < N_TOT) {
    int b = y[i] * 2 + l[i];
    unsigned pos = bstart[b] + atomicAdd(&cnt2[b], 1u);
    perm[pos] = i;
  }
}

// ---------------- build per-class K blocks ----------------
__global__ __launch_bounds__(256) void build_k(const float* __restrict__ sf, const float* __restrict__ tf,
                                               const float* __restrict__ xn, const int* __restrict__ perm,
                                               const int* __restrict__ meta, const float* __restrict__ scal,
                                               float* __restrict__ gK) {
  const int c = blockIdx.z;
  const int n = meta[c];
  const int cs = meta[64 + c];
  const int bo = meta[96 + c];
  const int tx = threadIdx.x, ty = threadIdx.y;
  const int i0 = blockIdx.y * 16, j0 = blockIdx.x * 16;
  if (i0 >= n || j0 >= n) return;
  __shared__ float As[16][260];
  __shared__ float Bs[16][260];
  __shared__ int ra[16];
  __shared__ int rb[16];
  int tid = ty * 16 + tx;
  if (tid < 16) { int il = i0 + tid; ra[tid] = (il < n) ? perm[cs + il] : -1; }
  else if (tid < 32) { int jl = j0 + tid - 16; rb[tid - 16] = (jl < n) ? perm[cs + jl] : -1; }
  __syncthreads();
  for (int e = tid; e < 1024; e += 256) {
    int r = e >> 6, q = e & 63;
    int g = ra[r];
    if (g >= 0) {
      const float* src = (g < N_SRC) ? (sf + (size_t)g * DIMF) : (tf + (size_t)(g - N_SRC) * DIMF);
      ((float4*)&As[r][q * 4])[0] = ((const float4*)src)[q];
    }
    int g2 = rb[r];
    if (g2 >= 0) {
      const float* src = (g2 < N_SRC) ? (sf + (size_t)g2 * DIMF) : (tf + (size_t)(g2 - N_SRC) * DIMF);
      ((float4*)&Bs[r][q * 4])[0] = ((const float4*)src)[q];
    }
  }
  __syncthreads();
  int il = i0 + ty, jl = j0 + tx;
  if (il < n && jl < n) {
    float dot = 0.f;
    const float4* a4 = (const float4*)&As[ty][0];
    const float4* b4 = (const float4*)&Bs[tx][0];
#pragma unroll 16
    for (int q = 0; q < 64; q++) {
      float4 a = a4[q], b = b4[q];
      dot += a.x * b.x + a.y * b.y + a.z * b.z + a.w * b.w;
    }
    int gi = ra[ty], gj = rb[tx];
    float d = xn[gi] + xn[gj] - 2.f * dot;
    gK[(size_t)bo + (size_t)il * n + jl] = expf(-d / scal[0]);
  }
}

// ---------------- per-(class,domain) damped Newton ----------------
// R3: reliable exits (gmax<5e-6, step exit, cap 12), all matvecs as
// contiguous per-thread row reads (K symmetry), triangular solves in one
// wave with register pv + shfl broadcast (no barriers).
__global__ __launch_bounds__(256) void solver_k(const float* __restrict__ gK, const int* __restrict__ meta,
                                                const float* __restrict__ scal, double* __restrict__ acc) {
  const int c = blockIdx.x >> 1, d = blockIdx.x & 1;
  const int n = meta[c];
  const int m0 = meta[32 + c];
  const int m = d ? (n - m0) : m0;
  const int c0 = d ? m0 : 0;
  const int bo = meta[96 + c];
  const float gamma = scal[1 + d];
  const int tid = threadIdx.x;

  __shared__ float H[MAXM * HST];      // 50624 B
  __shared__ float rowb[8][RST];       // 3712 B
  __shared__ float Av[MAXN];
  __shared__ float Bv[MAXN];
  __shared__ float Sv[MAXN];
  __shared__ float sqS[MAXN];
  __shared__ float bc[MAXM];
  __shared__ float th[MAXM];
  __shared__ float gv[MAXM];
  __shared__ float pv[MAXM];
  __shared__ double red[16];

  const float* K = gK + bo;
  const int st = n;
  const int P = m * (m + 1) / 2;
  const int mt = (m + 3) >> 2;
  const int mp4 = mt << 2;
  const int Pt = mt * (mt + 1) / 2;

  // packed lower-tri (j>=k) element slots for the factor
  int ejk[NSLOT];
#pragma unroll
  for (int s2 = 0; s2 < NSLOT; s2++) {
    int e = tid + (s2 << 8);
    int j = (int)((sqrtf(8.f * (float)e + 1.f) - 1.f) * 0.5f);
    while ((j + 1) * (j + 2) / 2 <= e) ++j;
    while (j * (j + 1) / 2 > e) --j;
    ejk[s2] = (j << 16) | (e - j * (j + 1) / 2);
  }
  // 4x4 tile slots for the H build
  int tji[NTILE];
#pragma unroll
  for (int s2 = 0; s2 < NTILE; s2++) {
    int t = tid + (s2 << 8);
    int ja = (int)((sqrtf(8.f * (float)t + 1.f) - 1.f) * 0.5f);
    while ((ja + 1) * (ja + 2) / 2 <= t) ++ja;
    while (ja * (ja + 1) / 2 > t) --ja;
    tji[s2] = (ja << 8) | (t - ja * (ja + 1) / 2);
  }

  // b_j = (1/N) * col-sum of same-domain block = row read via symmetry
  for (int j = tid; j < m; j += 256) {
    const float* Kr = K + (size_t)(c0 + j) * st + c0;
    float sum = 0.f;
    int r = 0;
    for (; r + 7 < m; r += 8)
      sum += Kr[r] + Kr[r + 1] + Kr[r + 2] + Kr[r + 3] + Kr[r + 4] + Kr[r + 5] + Kr[r + 6] + Kr[r + 7];
    for (; r < m; r++) sum += Kr[r];
    bc[j] = sum * (1.0f / 4096.0f);
    th[j] = 0.f;
  }
  __syncthreads();

  bool done = false;
  for (int it = 0; it < 12; it++) {
    // ---- A_i = dot(K row i [c0..c0+m), th) : contiguous per-thread ----
    for (int i = tid; i < n; i += 256) {
      const float* Kr = K + (size_t)i * st + c0;
      float a = 0.f;
      int j = 0;
      for (; j + 7 < m; j += 8)
        a += th[j] * Kr[j] + th[j + 1] * Kr[j + 1] + th[j + 2] * Kr[j + 2] + th[j + 3] * Kr[j + 3]
           + th[j + 4] * Kr[j + 4] + th[j + 5] * Kr[j + 5] + th[j + 6] * Kr[j + 6] + th[j + 7] * Kr[j + 7];
      for (; j < m; j++) a += th[j] * Kr[j];
      Av[i] = a;
    }
    __syncthreads();
    // ---- S, sqrt(S), obj ----
    double o = 0.0;
    for (int i = tid; i < n; i += 256) {
      float si = gamma * expf(fminf(Av[i] - 1.f, 30.f));
      Sv[i] = si; sqS[i] = sqrtf(si); o += (double)si;
    }
    for (int j = tid; j < m; j += 256) {
      float t_ = th[j];
      o += (double)(-bc[j] * t_ + LAMBDA * t_ * t_);
    }
    __syncthreads();  // Sv ready for gradient
    // ---- gradient: g_j = dot(K row c0+j, Sv) - bc + 2*lambda*th ----
    double gm = 0.0;
    for (int j = tid; j < m; j += 256) {
      const float* Kr = K + (size_t)(c0 + j) * st;
      float s_ = 0.f;
      int i = 0;
      for (; i + 7 < n; i += 8)
        s_ += Kr[i] * Sv[i] + Kr[i + 1] * Sv[i + 1] + Kr[i + 2] * Sv[i + 2] + Kr[i + 3] * Sv[i + 3]
            + Kr[i + 4] * Sv[i + 4] + Kr[i + 5] * Sv[i + 5] + Kr[i + 6] * Sv[i + 6] + Kr[i + 7] * Sv[i + 7];
      for (; i < n; i++) s_ += Kr[i] * Sv[i];
      float g = s_ - bc[j] + 2.f * LAMBDA * th[j];
      gv[j] = g;
      double ag = fabs((double)g); if (ag > gm) gm = ag;
    }
    double obj, gmax;
    blockReduceSumMax(o, gm, red, obj, gmax);
    if (gmax < 5e-6) { done = true; break; }   // Av/Sv valid; value err <<< threshold

    // ---- H = W^T W + 2*lambda*I, W = diag(sqrt(S)) K~; 4x4 reg tiles ----
    float hc[NTILE * 16];
#pragma unroll
    for (int q = 0; q < NTILE * 16; q++) hc[q] = 0.f;
    for (int ib = 0; ib < n; ib += 8) {
      int nr = min(8, n - ib);
      for (int ii = 0; ii < nr; ii++) {
        float sq = sqS[ib + ii];
        for (int j = tid; j < mp4; j += 256)
          rowb[ii][j] = (j < m) ? K[(size_t)(ib + ii) * st + c0 + j] * sq : 0.f;
      }
      __syncthreads();
      for (int ii = 0; ii < nr; ii++) {
#pragma unroll
        for (int s2 = 0; s2 < NTILE; s2++) {
          if (tid + (s2 << 8) < Pt) {
            int ja = tji[s2] >> 8, ka = tji[s2] & 255;
            float4 wj = *(const float4*)&rowb[ii][4 * ja];
            float4 wk = *(const float4*)&rowb[ii][4 * ka];
            float* h = hc + s2 * 16;
            h[0]  += wj.x * wk.x; h[1]  += wj.x * wk.y; h[2]  += wj.x * wk.z; h[3]  += wj.x * wk.w;
            h[4]  += wj.y * wk.x; h[5]  += wj.y * wk.y; h[6]  += wj.y * wk.z; h[7]  += wj.y * wk.w;
            h[8]  += wj.z * wk.x; h[9]  += wj.z * wk.y; h[10] += wj.z * wk.z; h[11] += wj.z * wk.w;
            h[12] += wj.w * wk.x; h[13] += wj.w * wk.y; h[14] += wj.w * wk.z; h[15] += wj.w * wk.w;
          }
        }
      }
      __syncthreads();
    }
#pragma unroll
    for (int s2 = 0; s2 < NTILE; s2++) {
      int t = tid + (s2 << 8);
      if (t < Pt) {
        int ja = tji[s2] >> 8, ka = tji[s2] & 255;
#pragma unroll
        for (int a = 0; a < 4; a++) {
          int j = 4 * ja + a;
          if (j < m) {
#pragma unroll
            for (int b = 0; b < 4; b++) {
              int k = 4 * ka + b;
              if (k <= j) H[j * HST + k] = hc[s2 * 16 + a * 4 + b];
            }
          }
        }
      }
    }
    __syncthreads();
    for (int j = tid; j < m; j += 256) H[j * HST + j] += 2.f * LAMBDA;
    __syncthreads();

    // ---- parallel right-looking LDL^T (unscaled columns; D on diag) ----
    for (int kk = 0; kk < m - 1; kk++) {
      float iv = 1.f / H[kk * HST + kk];
#pragma unroll
      for (int s2 = 0; s2 < NSLOT; s2++) {
        int e = tid + (s2 << 8);
        if (e < P) {
          int j = ejk[s2] >> 16, k = ejk[s2] & 0xffff;
          if (k > kk) H[j * HST + k] -= H[j * HST + kk] * iv * H[k * HST + kk];
        }
      }
      __syncthreads();
    }

    // ---- triangular solves: wave 0, register pv + shfl broadcast ----
    if (tid < 64) {
      int l = tid, j1 = tid + 64;
      float pA = (l < m)  ? -gv[l]  : 0.f;
      float pB = (j1 < m) ? -gv[j1] : 0.f;
      float dA = (l < m)  ? 1.f / H[l * HST + l]   : 0.f;
      float dB = (j1 < m) ? 1.f / H[j1 * HST + j1] : 0.f;
      // forward: (L) with zk = pv[kk]*idd[kk]
      for (int kk = 0; kk < m - 1; kk++) {
        float psrc = (kk < 64) ? __shfl(pA, kk, 64) : __shfl(pB, kk - 64, 64);
        float dsrc = (kk < 64) ? __shfl(dA, kk, 64) : __shfl(dB, kk - 64, 64);
        float zk = psrc * dsrc;
        if (l > kk && l < m)   pA -= H[l * HST + kk] * zk;
        if (j1 > kk && j1 < m) pB -= H[j1 * HST + kk] * zk;
      }
      pA *= dA; pB *= dB;
      // backward: (L^T) pv[t] -= H[kk][t]*idd[t]*pv[kk], kk descending
      for (int kk = m - 1; kk >= 1; kk--) {
        float pk = (kk < 64) ? __shfl(pA, kk, 64) : __shfl(pB, kk - 64, 64);
        if (l < kk)  pA -= H[kk * HST + l]  * dA * pk;
        if (j1 < kk) pB -= H[kk * HST + j1] * dB * pk;
      }
      if (l < m)  pv[l] = pA;
      if (j1 < m) pv[j1] = pB;
    }
    __syncthreads();

    // ---- B_i = dot(K row i, pv) ; gtp ; pmax ----
    for (int i = tid; i < n; i += 256) {
      const float* Kr = K + (size_t)i * st + c0;
      float bsum = 0.f;
      int j = 0;
      for (; j + 7 < m; j += 8)
        bsum += pv[j] * Kr[j] + pv[j + 1] * Kr[j + 1] + pv[j + 2] * Kr[j + 2] + pv[j + 3] * Kr[j + 3]
              + pv[j + 4] * Kr[j + 4] + pv[j + 5] * Kr[j + 5] + pv[j + 6] * Kr[j + 6] + pv[j + 7] * Kr[j + 7];
      for (; j < m; j++) bsum += pv[j] * Kr[j];
      Bv[i] = bsum;
    }
    double gtp_l = 0.0, pm = 0.0;
    for (int j = tid; j < m; j += 256) {
      gtp_l += (double)gv[j] * (double)pv[j];
      double ap = fabs((double)pv[j]); if (ap > pm) pm = ap;
    }
    double gtp, pmax;
    blockReduceSumMax(gtp_l, pm, red, gtp, pmax);
    if (!(gtp < 0.0)) { done = true; break; }  // numerically converged; Av/Sv valid
    // ---- Armijo line search ----
    float t = 1.f;
    for (int ls = 0; ls < 10; ls++) {
      double ol = 0.0;
      for (int i = tid; i < n; i += 256)
        ol += (double)(gamma * expf(fminf(Av[i] + t * Bv[i] - 1.f, 30.f)));
      for (int j = tid; j < m; j += 256) {
        float tj = th[j] + t * pv[j];
        ol += (double)(-bc[j] * tj + LAMBDA * tj * tj);
      }
      double ot = blockReduceSum(ol, red);
      if (ot <= obj + 1e-4 * (double)t * gtp) break;
      t *= 0.5f;
    }
    for (int j = tid; j < m; j += 256) th[j] += t * pv[j];
    __syncthreads();
    if ((double)t * pmax < 1e-7) break;   // step negligible; recompute path below
  }

  if (!done) {
    // recompute Av/Sv for the final theta
    for (int i = tid; i < n; i += 256) {
      const float* Kr = K + (size_t)i * st + c0;
      float a = 0.f;
      for (int j = 0; j < m; j++) a += th[j] * Kr[j];
      Av[i] = a;
    }
    __syncthreads();
    for (int i = tid; i < n; i += 256) Sv[i] = gamma * expf(fminf(Av[i] - 1.f, 30.f));
    __syncthreads();
  }
  double t1l = 0.0, t2l = 0.0;
  for (int i = tid; i < n; i += 256) t2l += (double)Sv[i];
  for (int j = tid; j < m; j += 256) t1l += (double)(bc[j] * th[j]);
  double t1 = blockReduceSum(t1l, red);
  double t2 = blockReduceSum(t2l, red);
  if (tid == 0) {
    atomicAdd(&acc[0], t1);
    atomicAdd(&acc[1], t2);
  }
}

__global__ void final_k(const double* __restrict__ acc, float* __restrict__ out) {
  out[0] = (float)(acc[0] - acc[1]);
}

// ---------------- launcher ----------------
extern "C" void kernel_launch(void* const* d_in, const int* in_sizes, int n_in,
                              void* d_out, int out_size, void* d_ws, size_t ws_size,
                              hipStream_t stream) {
  const float* sf = (const float*)d_in[0];
  const float* tf = (const float*)d_in[1];
  const int* y = (const int*)d_in[2];
  const int* l = (const int*)d_in[3];
  char* ws = (char*)d_ws;

  double*   acc    = (double*)(ws + WS_ACC);
  unsigned* hist0  = (unsigned*)(ws + WS_HIST0);
  unsigned* histA  = (unsigned*)(ws + WS_HISTA);
  unsigned* histB  = (unsigned*)(ws + WS_HISTB);
  unsigned* h2A    = (unsigned*)(ws + WS_H2A);
  unsigned* h2B    = (unsigned*)(ws + WS_H2B);
  unsigned* state  = (unsigned*)(ws + WS_STATE);
  unsigned* cnt    = (unsigned*)(ws + WS_CNT);
  unsigned* cnt2   = (unsigned*)(ws + WS_CNT2);
  unsigned* bstart = (unsigned*)(ws + WS_BSTART);
  int*      meta   = (int*)(ws + WS_META);
  float*    scal   = (float*)(ws + WS_SCAL);
  int*      perm   = (int*)(ws + WS_PERM);
  float*    xnp    = (float*)(ws + WS_XN);
  float*    Ds     = (float*)(ws + WS_DS);
  float*    gK     = (float*)(ws + WS_KBLK);

  hipMemsetAsync(d_ws, 0, ZERO_BYTES, stream);
  hipLaunchKernelGGL(xn_kernel, dim3(1024), dim3(256), 0, stream, sf, tf, xnp);
  hipLaunchKernelGGL(dist_k, dim3(32, 32), dim3(16, 16), 0, stream, sf, xnp, Ds);
  hipLaunchKernelGGL(hist0_k, dim3(512), dim3(256), 0, stream, Ds, hist0);
  hipLaunchKernelGGL(scan0_k, dim3(1), dim3(256), 0, stream, hist0, state);
  hipLaunchKernelGGL(hist1_k, dim3(512), dim3(256), 0, stream, Ds, state, histA, histB);
  hipLaunchKernelGGL(scan1_k, dim3(1), dim3(256), 0, stream, histA, histB, state);
  hipLaunchKernelGGL(hist2_k, dim3(512), dim3(256), 0, stream, Ds, state, h2A, h2B);
  hipLaunchKernelGGL(scan2_k, dim3(1), dim3(256), 0, stream, h2A, h2B, state, scal);
  hipLaunchKernelGGL(cnt_k, dim3(16), dim3(256), 0, stream, y, l, cnt);
  hipLaunchKernelGGL(scank_k, dim3(1), dim3(1), 0, stream, cnt, bstart, meta, scal);
  hipLaunchKernelGGL(scat_k, dim3(16), dim3(256), 0, stream, y, l, bstart, cnt2, perm);
  hipLaunchKernelGGL(build_k, dim3(16, 16, NCLASS), dim3(16, 16), 0, stream, sf, tf, xnp, perm, meta, scal, gK);
  hipLaunchKernelGGL(solver_k, dim3(62), dim3(256), 0, stream, gK, meta, scal, acc);
  hipLaunchKernelGGL(final_k, dim3(1), dim3(1), 0, stream, acc, (float*)d_out);
}

// Round 4
// 854.183 us; speedup vs baseline: 4.5846x; 1.1201x over previous
//
#include <hip/hip_runtime.h>
#include <math.h>

#define N_TOT   4096
#define N_SRC   2048
#define DIMF    256
#define NCLASS  31
#define LAMBDA  0.01f

// median target ranks (0-indexed) among 4192256 non-NaN values
#define K_MED1  2096127LL
#define K_MED2  2096128LL

// ---- ws layout (bytes) ----
#define WS_ACC    0           // 2 doubles
#define WS_HIST0  64          // 4096 u32
#define WS_HISTA  16448       // 4096 u32
#define WS_HISTB  32832       // 4096 u32
#define WS_H2A    49216       // 256 u32
#define WS_H2B    50240       // 256 u32
#define WS_STATE  51264       // 64 u32
#define WS_CNT    51520       // 64 u32
#define WS_CNT2   51776       // 64 u32
#define WS_BSTART 52032       // 64 u32
#define WS_META   52288       // 128 i32: ncls[32], m0c[32], cstart[32], blkoff[32]
#define WS_SCAL   52800       // 16 f32: [0]=sigma, [1]=gamma0, [2]=gamma1
#define ZERO_BYTES 53248
#define WS_PERM   53248       // 4096 i32
#define WS_XN     69632       // 4096 f32
#define WS_DS     1048576     // 2048*2048 f32 (16.78 MB)
#define WS_KBLK   17825792    // class K blocks (8 MB budget)

// solver capacity (binomial(4096,1/62): mean 66, sd 8 -> MAXM=112 is +5.7 sigma)
#define MAXM 112
#define MAXN 256
#define HST  113
#define NSLOT 25   // ceil(112*113/2 / 256)  -- element slots (factor)
#define NTILE 2    // ceil(ceil(112/4)*(..+1)/2 / 256)
#define RST  116   // rowb stride
#define ROWS 16    // H-build staging rows

// ---------------- reductions ----------------
__device__ __forceinline__ double blockReduceSum(double v, double* red) {
#pragma unroll
  for (int o = 32; o > 0; o >>= 1) v += __shfl_down(v, o, 64);
  int w = threadIdx.x >> 6, lane = threadIdx.x & 63;
  __syncthreads();
  if (lane == 0) red[w] = v;
  __syncthreads();
  return red[0] + red[1] + red[2] + red[3];
}

__device__ __forceinline__ void blockReduceSumMax(double s, double mx, double* red,
                                                  double& os, double& om) {
#pragma unroll
  for (int o = 32; o > 0; o >>= 1) {
    s += __shfl_down(s, o, 64);
    double u = __shfl_down(mx, o, 64);
    mx = fmax(mx, u);
  }
  int w = threadIdx.x >> 6, lane = threadIdx.x & 63;
  __syncthreads();
  if (lane == 0) { red[w] = s; red[4 + w] = mx; }
  __syncthreads();
  os = red[0] + red[1] + red[2] + red[3];
  om = fmax(fmax(red[4], red[5]), fmax(red[6], red[7]));
}

// ---------------- row norms ----------------
__global__ __launch_bounds__(256) void xn_kernel(const float* __restrict__ sf,
                                                 const float* __restrict__ tf,
                                                 float* __restrict__ xn) {
  int wid = threadIdx.x >> 6, lane = threadIdx.x & 63;
  int row = blockIdx.x * 4 + wid;
  const float* src = (row < N_SRC) ? (sf + (size_t)row * DIMF) : (tf + (size_t)(row - N_SRC) * DIMF);
  float4 v = ((const float4*)src)[lane];
  float s = v.x * v.x + v.y * v.y + v.z * v.z + v.w * v.w;
#pragma unroll
  for (int o = 32; o > 0; o >>= 1) s += __shfl_down(s, o, 64);
  if (lane == 0) xn[row] = s;
}

// ---------------- source pairwise sq-dists (for median) ----------------
__global__ __launch_bounds__(256) void dist_k(const float* __restrict__ sf,
                                              const float* __restrict__ xn,
                                              float* __restrict__ Ds) {
  __shared__ float As[16][68];
  __shared__ float Bs[16][68];
  const int tx = threadIdx.x, ty = threadIdx.y;
  const int tid = ty * 16 + tx;
  const int R = blockIdx.y * 64, C = blockIdx.x * 64;
  float acc[4][4] = {};
  for (int kc = 0; kc < 256; kc += 16) {
    int i = tid >> 2, q = tid & 3;
    float4 va = ((const float4*)(sf + (size_t)(R + i) * 256 + kc))[q];
    As[q * 4 + 0][i] = va.x; As[q * 4 + 1][i] = va.y; As[q * 4 + 2][i] = va.z; As[q * 4 + 3][i] = va.w;
    float4 vb = ((const float4*)(sf + (size_t)(C + i) * 256 + kc))[q];
    Bs[q * 4 + 0][i] = vb.x; Bs[q * 4 + 1][i] = vb.y; Bs[q * 4 + 2][i] = vb.z; Bs[q * 4 + 3][i] = vb.w;
    __syncthreads();
#pragma unroll
    for (int k = 0; k < 16; k++) {
      float4 a = *(const float4*)&As[k][ty * 4];
      float4 b = *(const float4*)&Bs[k][tx * 4];
      acc[0][0] += a.x * b.x; acc[0][1] += a.x * b.y; acc[0][2] += a.x * b.z; acc[0][3] += a.x * b.w;
      acc[1][0] += a.y * b.x; acc[1][1] += a.y * b.y; acc[1][2] += a.y * b.z; acc[1][3] += a.y * b.w;
      acc[2][0] += a.z * b.x; acc[2][1] += a.z * b.y; acc[2][2] += a.z * b.z; acc[2][3] += a.z * b.w;
      acc[3][0] += a.w * b.x; acc[3][1] += a.w * b.y; acc[3][2] += a.w * b.z; acc[3][3] += a.w * b.w;
    }
    __syncthreads();
  }
  const float INF = __int_as_float(0x7f800000);
  int jbase = C + tx * 4;
  float xnj0 = xn[jbase + 0], xnj1 = xn[jbase + 1], xnj2 = xn[jbase + 2], xnj3 = xn[jbase + 3];
#pragma unroll
  for (int r = 0; r < 4; r++) {
    int i = R + ty * 4 + r;
    float xni = xn[i];
    float4 o;
    o.x = fmaxf(xni + xnj0 - 2.f * acc[r][0], 0.f);
    o.y = fmaxf(xni + xnj1 - 2.f * acc[r][1], 0.f);
    o.z = fmaxf(xni + xnj2 - 2.f * acc[r][2], 0.f);
    o.w = fmaxf(xni + xnj3 - 2.f * acc[r][3], 0.f);
    if (i == jbase + 0) o.x = INF;
    if (i == jbase + 1) o.y = INF;
    if (i == jbase + 2) o.z = INF;
    if (i == jbase + 3) o.w = INF;
    ((float4*)&Ds[(size_t)i * 2048 + jbase])[0] = o;
  }
}

// ---------------- radix-select median (3 passes) ----------------
__global__ __launch_bounds__(256) void hist0_k(const float* __restrict__ Ds, unsigned* __restrict__ h) {
  __shared__ unsigned lh[4096];
  for (int i = threadIdx.x; i < 4096; i += 256) lh[i] = 0;
  __syncthreads();
  unsigned total = 2048u * 2048u;
  for (unsigned idx = blockIdx.x * 256 + threadIdx.x; idx < total; idx += gridDim.x * 256) {
    unsigned u = __float_as_uint(Ds[idx]);
    atomicAdd(&lh[u >> 20], 1u);
  }
  __syncthreads();
  for (int i = threadIdx.x; i < 4096; i += 256) if (lh[i]) atomicAdd(&h[i], lh[i]);
}

__global__ __launch_bounds__(256) void hist1_k(const float* __restrict__ Ds, const unsigned* __restrict__ st,
                                               unsigned* __restrict__ hA, unsigned* __restrict__ hB) {
  __shared__ unsigned lA[4096];
  __shared__ unsigned lB[4096];
  for (int i = threadIdx.x; i < 4096; i += 256) { lA[i] = 0; lB[i] = 0; }
  __syncthreads();
  unsigned s0 = st[0], s1 = st[2];
  unsigned total = 2048u * 2048u;
  for (unsigned idx = blockIdx.x * 256 + threadIdx.x; idx < total; idx += gridDim.x * 256) {
    unsigned u = __float_as_uint(Ds[idx]);
    unsigned hi = u >> 20, mid = (u >> 8) & 0xFFFu;
    if (hi == s0) atomicAdd(&lA[mid], 1u);
    if (hi == s1) atomicAdd(&lB[mid], 1u);
  }
  __syncthreads();
  for (int i = threadIdx.x; i < 4096; i += 256) {
    if (lA[i]) atomicAdd(&hA[i], lA[i]);
    if (lB[i]) atomicAdd(&hB[i], lB[i]);
  }
}

__global__ __launch_bounds__(256) void hist2_k(const float* __restrict__ Ds, const unsigned* __restrict__ st,
                                               unsigned* __restrict__ hA, unsigned* __restrict__ hB) {
  __shared__ unsigned lA[256];
  __shared__ unsigned lB[256];
  if (threadIdx.x < 256) { lA[threadIdx.x] = 0; lB[threadIdx.x] = 0; }
  __syncthreads();
  unsigned p0 = (st[0] << 12) | st[4];
  unsigned p1 = (st[2] << 12) | st[6];
  unsigned total = 2048u * 2048u;
  for (unsigned idx = blockIdx.x * 256 + threadIdx.x; idx < total; idx += gridDim.x * 256) {
    unsigned u = __float_as_uint(Ds[idx]);
    unsigned pre = u >> 8;
    if (pre == p0) atomicAdd(&lA[u & 0xFFu], 1u);
    if (pre == p1) atomicAdd(&lB[u & 0xFFu], 1u);
  }
  __syncthreads();
  if (lA[threadIdx.x]) atomicAdd(&hA[threadIdx.x], lA[threadIdx.x]);
  if (lB[threadIdx.x]) atomicAdd(&hB[threadIdx.x], lB[threadIdx.x]);
}

__device__ void scan_find(const unsigned* hist, int nbins, long long k, unsigned* shOut) {
  __shared__ long long tsum[256];
  int per = nbins / 256;
  long long s = 0;
  for (int q = 0; q < per; q++) s += hist[threadIdx.x * per + q];
  tsum[threadIdx.x] = s;
  __syncthreads();
  if (threadIdx.x == 0) {
    long long run = 0;
    for (int t = 0; t < 256; t++) { long long v = tsum[t]; tsum[t] = run; run += v; }
  }
  __syncthreads();
  long long run = tsum[threadIdx.x];
  for (int q = 0; q < per; q++) {
    unsigned c = hist[threadIdx.x * per + q];
    if (k >= run && k < run + (long long)c) { shOut[0] = (unsigned)(threadIdx.x * per + q); shOut[1] = (unsigned)(k - run); }
    run += c;
  }
  __syncthreads();
}

__global__ __launch_bounds__(256) void scan0_k(const unsigned* __restrict__ h, unsigned* __restrict__ st) {
  __shared__ unsigned r0[2];
  __shared__ unsigned r1[2];
  scan_find(h, 4096, K_MED1, r0);
  scan_find(h, 4096, K_MED2, r1);
  if (threadIdx.x == 0) { st[0] = r0[0]; st[1] = r0[1]; st[2] = r1[0]; st[3] = r1[1]; }
}

__global__ __launch_bounds__(256) void scan1_k(const unsigned* __restrict__ hA, const unsigned* __restrict__ hB,
                                               unsigned* __restrict__ st) {
  __shared__ unsigned r0[2];
  __shared__ unsigned r1[2];
  long long kA = (long long)st[1];
  long long kB = (long long)st[3];
  scan_find(hA, 4096, kA, r0);
  scan_find(hB, 4096, kB, r1);
  if (threadIdx.x == 0) { st[4] = r0[0]; st[5] = r0[1]; st[6] = r1[0]; st[7] = r1[1]; }
}

__global__ __launch_bounds__(256) void scan2_k(const unsigned* __restrict__ hA, const unsigned* __restrict__ hB,
                                               unsigned* __restrict__ st, float* __restrict__ scal) {
  __shared__ unsigned r0[2];
  __shared__ unsigned r1[2];
  long long kA = (long long)st[5];
  long long kB = (long long)st[7];
  scan_find(hA, 256, kA, r0);
  scan_find(hB, 256, kB, r1);
  if (threadIdx.x == 0) {
    unsigned v1 = (st[0] << 20) | (st[4] << 8) | r0[0];
    unsigned v2 = (st[2] << 20) | (st[6] << 8) | r1[0];
    scal[0] = 0.5f * (__uint_as_float(v1) + __uint_as_float(v2));  // sigma
  }
}

// ---------------- class/domain bucketing ----------------
__global__ void cnt_k(const int* __restrict__ y, const int* __restrict__ l, unsigned* __restrict__ cnt) {
  int i = blockIdx.x * 256 + threadIdx.x;
  if (i < N_TOT) atomicAdd(&cnt[y[i] * 2 + l[i]], 1u);
}

__global__ void scank_k(const unsigned* __restrict__ cnt, unsigned* __restrict__ bstart,
                        int* __restrict__ meta, float* __restrict__ scal) {
  unsigned run = 0;
  for (int b = 0; b < 62; b++) { bstart[b] = run; run += cnt[b]; }
  int* ncls = meta; int* m0c = meta + 32; int* cstart = meta + 64; int* blkoff = meta + 96;
  unsigned run2 = 0, cnt0 = 0;
  for (int c = 0; c < NCLASS; c++) {
    int n = (int)(cnt[2 * c] + cnt[2 * c + 1]);
    ncls[c] = n; m0c[c] = (int)cnt[2 * c]; cstart[c] = (int)bstart[2 * c];
    blkoff[c] = (int)run2; run2 += (unsigned)(n * n);
    cnt0 += cnt[2 * c];
  }
  scal[1] = (float)((double)cnt0 / (4096.0 * 4096.0));
  scal[2] = (float)((double)(N_TOT - cnt0) / (4096.0 * 4096.0));
}

__global__ void scat_k(const int* __restrict__ y, const int* __restrict__ l,
                       const unsigned* __restrict__ bstart, unsigned* __restrict__ cnt2,
                       int* __restrict__ perm) {
  int i = blockIdx.x * 256 + threadIdx.x;
  if (i < N_TOT) {
    int b = y[i] * 2 + l[i];
    unsigned pos = bstart[b] + atomicAdd(&cnt2[b], 1u);
    perm[pos] = i;
  }
}

// ---------------- build per-class K blocks ----------------
__global__ __launch_bounds__(256) void build_k(const float* __restrict__ sf, const float* __restrict__ tf,
                                               const float* __restrict__ xn, const int* __restrict__ perm,
                                               const int* __restrict__ meta, const float* __restrict__ scal,
                                               float* __restrict__ gK) {
  const int c = blockIdx.z;
  const int n = meta[c];
  const int cs = meta[64 + c];
  const int bo = meta[96 + c];
  const int tx = threadIdx.x, ty = threadIdx.y;
  const int i0 = blockIdx.y * 16, j0 = blockIdx.x * 16;
  if (i0 >= n || j0 >= n) return;
  __shared__ float As[16][260];
  __shared__ float Bs[16][260];
  __shared__ int ra[16];
  __shared__ int rb[16];
  int tid = ty * 16 + tx;
  if (tid < 16) { int il = i0 + tid; ra[tid] = (il < n) ? perm[cs + il] : -1; }
  else if (tid < 32) { int jl = j0 + tid - 16; rb[tid - 16] = (jl < n) ? perm[cs + jl] : -1; }
  __syncthreads();
  for (int e = tid; e < 1024; e += 256) {
    int r = e >> 6, q = e & 63;
    int g = ra[r];
    if (g >= 0) {
      const float* src = (g < N_SRC) ? (sf + (size_t)g * DIMF) : (tf + (size_t)(g - N_SRC) * DIMF);
      ((float4*)&As[r][q * 4])[0] = ((const float4*)src)[q];
    }
    int g2 = rb[r];
    if (g2 >= 0) {
      const float* src = (g2 < N_SRC) ? (sf + (size_t)g2 * DIMF) : (tf + (size_t)(g2 - N_SRC) * DIMF);
      ((float4*)&Bs[r][q * 4])[0] = ((const float4*)src)[q];
    }
  }
  __syncthreads();
  int il = i0 + ty, jl = j0 + tx;
  if (il < n && jl < n) {
    float dot = 0.f;
    const float4* a4 = (const float4*)&As[ty][0];
    const float4* b4 = (const float4*)&Bs[tx][0];
#pragma unroll 16
    for (int q = 0; q < 64; q++) {
      float4 a = a4[q], b = b4[q];
      dot += a.x * b.x + a.y * b.y + a.z * b.z + a.w * b.w;
    }
    int gi = ra[ty], gj = rb[tx];
    float d = xn[gi] + xn[gj] - 2.f * dot;
    gK[(size_t)bo + (size_t)il * n + jl] = expf(-d / scal[0]);
  }
}

// ---------------- per-(class,domain) damped Newton ----------------
// R4: simplified Newton — H built+factored once (refactor only if line search
// damps or staleness), Armijo+Bv skipped when decrement < 1e-4, gtp/pmax fused
// into the wave-0 triangular solve. Cheap iteration = ~6 barriers.
__global__ __launch_bounds__(256) void solver_k(const float* __restrict__ gK, const int* __restrict__ meta,
                                                const float* __restrict__ scal, double* __restrict__ acc) {
  const int c = blockIdx.x >> 1, d = blockIdx.x & 1;
  const int n = meta[c];
  const int m0 = meta[32 + c];
  const int m = d ? (n - m0) : m0;
  const int c0 = d ? m0 : 0;
  const int bo = meta[96 + c];
  const float gamma = scal[1 + d];
  const int tid = threadIdx.x;

  __shared__ float H[MAXM * HST];      // 50624 B
  __shared__ float rowb[ROWS][RST];    // 7424 B
  __shared__ float Av[MAXN];
  __shared__ float Bv[MAXN];
  __shared__ float Sv[MAXN];
  __shared__ float sqS[MAXN];
  __shared__ float bc[MAXM];
  __shared__ float th[MAXM];
  __shared__ float gv[MAXM];
  __shared__ float pv[MAXM];
  __shared__ double red[16];

  const float* K = gK + bo;
  const int st = n;
  const int P = m * (m + 1) / 2;
  const int mt = (m + 3) >> 2;
  const int mp4 = mt << 2;
  const int Pt = mt * (mt + 1) / 2;

  // packed lower-tri (j>=k) element slots for the factor
  int ejk[NSLOT];
#pragma unroll
  for (int s2 = 0; s2 < NSLOT; s2++) {
    int e = tid + (s2 << 8);
    int j = (int)((sqrtf(8.f * (float)e + 1.f) - 1.f) * 0.5f);
    while ((j + 1) * (j + 2) / 2 <= e) ++j;
    while (j * (j + 1) / 2 > e) --j;
    ejk[s2] = (j << 16) | (e - j * (j + 1) / 2);
  }
  // 4x4 tile slots for the H build
  int tji[NTILE];
#pragma unroll
  for (int s2 = 0; s2 < NTILE; s2++) {
    int t = tid + (s2 << 8);
    int ja = (int)((sqrtf(8.f * (float)t + 1.f) - 1.f) * 0.5f);
    while ((ja + 1) * (ja + 2) / 2 <= t) ++ja;
    while (ja * (ja + 1) / 2 > t) --ja;
    tji[s2] = (ja << 8) | (t - ja * (ja + 1) / 2);
  }

  // b_j = (1/N) * col-sum of same-domain block = row read via symmetry
  for (int j = tid; j < m; j += 256) {
    const float* Kr = K + (size_t)(c0 + j) * st + c0;
    float sum = 0.f;
    int r = 0;
    for (; r + 7 < m; r += 8)
      sum += Kr[r] + Kr[r + 1] + Kr[r + 2] + Kr[r + 3] + Kr[r + 4] + Kr[r + 5] + Kr[r + 6] + Kr[r + 7];
    for (; r < m; r++) sum += Kr[r];
    bc[j] = sum * (1.0f / 4096.0f);
    th[j] = 0.f;
  }
  __syncthreads();

  bool done = false;
  bool haveF = false, forceF = false;
  int sinceF = 0;
  for (int it = 0; it < 30; it++) {
    // ---- A_i = dot(K row i [c0..c0+m), th) : contiguous per-thread ----
    if (it == 0) {
      for (int i = tid; i < n; i += 256) Av[i] = 0.f;
    } else {
      for (int i = tid; i < n; i += 256) {
        const float* Kr = K + (size_t)i * st + c0;
        float a = 0.f;
        int j = 0;
        for (; j + 7 < m; j += 8)
          a += th[j] * Kr[j] + th[j + 1] * Kr[j + 1] + th[j + 2] * Kr[j + 2] + th[j + 3] * Kr[j + 3]
             + th[j + 4] * Kr[j + 4] + th[j + 5] * Kr[j + 5] + th[j + 6] * Kr[j + 6] + th[j + 7] * Kr[j + 7];
        for (; j < m; j++) a += th[j] * Kr[j];
        Av[i] = a;
      }
    }
    __syncthreads();
    // ---- S, sqrt(S), obj ----
    double o = 0.0;
    for (int i = tid; i < n; i += 256) {
      float si = gamma * expf(fminf(Av[i] - 1.f, 30.f));
      Sv[i] = si; sqS[i] = sqrtf(si); o += (double)si;
    }
    for (int j = tid; j < m; j += 256) {
      float t_ = th[j];
      o += (double)(-bc[j] * t_ + LAMBDA * t_ * t_);
    }
    __syncthreads();  // Sv ready for gradient
    // ---- gradient: g_j = dot(K row c0+j, Sv) - bc + 2*lambda*th ----
    double gm = 0.0;
    for (int j = tid; j < m; j += 256) {
      const float* Kr = K + (size_t)(c0 + j) * st;
      float s_ = 0.f;
      int i = 0;
      for (; i + 7 < n; i += 8)
        s_ += Kr[i] * Sv[i] + Kr[i + 1] * Sv[i + 1] + Kr[i + 2] * Sv[i + 2] + Kr[i + 3] * Sv[i + 3]
            + Kr[i + 4] * Sv[i + 4] + Kr[i + 5] * Sv[i + 5] + Kr[i + 6] * Sv[i + 6] + Kr[i + 7] * Sv[i + 7];
      for (; i < n; i++) s_ += Kr[i] * Sv[i];
      float g = s_ - bc[j] + 2.f * LAMBDA * th[j];
      gv[j] = g;
      double ag = fabs((double)g); if (ag > gm) gm = ag;
    }
    double obj, gmax;
    blockReduceSumMax(o, gm, red, obj, gmax);
    if (gmax < 5e-6) { done = true; break; }   // Av/Sv valid; value err <<< threshold

    // ---- (re)build + factor H only when needed ----
    bool rebuild = (!haveF) || forceF || (sinceF >= 8);
    if (rebuild) {
      haveF = true; forceF = false; sinceF = 0;
      float hc[NTILE * 16];
#pragma unroll
      for (int q = 0; q < NTILE * 16; q++) hc[q] = 0.f;
      for (int ib = 0; ib < n; ib += ROWS) {
        int nr = min(ROWS, n - ib);
        for (int ii = 0; ii < nr; ii++) {
          float sq = sqS[ib + ii];
          for (int j = tid; j < mp4; j += 256)
            rowb[ii][j] = (j < m) ? K[(size_t)(ib + ii) * st + c0 + j] * sq : 0.f;
        }
        __syncthreads();
        for (int ii = 0; ii < nr; ii++) {
#pragma unroll
          for (int s2 = 0; s2 < NTILE; s2++) {
            if (tid + (s2 << 8) < Pt) {
              int ja = tji[s2] >> 8, ka = tji[s2] & 255;
              float4 wj = *(const float4*)&rowb[ii][4 * ja];
              float4 wk = *(const float4*)&rowb[ii][4 * ka];
              float* h = hc + s2 * 16;
              h[0]  += wj.x * wk.x; h[1]  += wj.x * wk.y; h[2]  += wj.x * wk.z; h[3]  += wj.x * wk.w;
              h[4]  += wj.y * wk.x; h[5]  += wj.y * wk.y; h[6]  += wj.y * wk.z; h[7]  += wj.y * wk.w;
              h[8]  += wj.z * wk.x; h[9]  += wj.z * wk.y; h[10] += wj.z * wk.z; h[11] += wj.z * wk.w;
              h[12] += wj.w * wk.x; h[13] += wj.w * wk.y; h[14] += wj.w * wk.z; h[15] += wj.w * wk.w;
            }
          }
        }
        __syncthreads();
      }
#pragma unroll
      for (int s2 = 0; s2 < NTILE; s2++) {
        int t = tid + (s2 << 8);
        if (t < Pt) {
          int ja = tji[s2] >> 8, ka = tji[s2] & 255;
#pragma unroll
          for (int a = 0; a < 4; a++) {
            int j = 4 * ja + a;
            if (j < m) {
#pragma unroll
              for (int b = 0; b < 4; b++) {
                int k = 4 * ka + b;
                if (k <= j) H[j * HST + k] = hc[s2 * 16 + a * 4 + b];
              }
            }
          }
        }
      }
      __syncthreads();
      for (int j = tid; j < m; j += 256) H[j * HST + j] += 2.f * LAMBDA;
      __syncthreads();
      // parallel right-looking LDL^T (unscaled columns; D on diag)
      for (int kk = 0; kk < m - 1; kk++) {
        float iv = 1.f / H[kk * HST + kk];
#pragma unroll
        for (int s2 = 0; s2 < NSLOT; s2++) {
          int e = tid + (s2 << 8);
          if (e < P) {
            int j = ejk[s2] >> 16, k = ejk[s2] & 0xffff;
            if (k > kk) H[j * HST + k] -= H[j * HST + kk] * iv * H[k * HST + kk];
          }
        }
        __syncthreads();
      }
    } else {
      sinceF++;
    }

    // ---- wave 0: triangular solves + gtp/pmax (shfl, no barriers) ----
    if (tid < 64) {
      int l = tid, j1 = tid + 64;
      float pA = (l < m)  ? -gv[l]  : 0.f;
      float pB = (j1 < m) ? -gv[j1] : 0.f;
      float dA = (l < m)  ? 1.f / H[l * HST + l]   : 0.f;
      float dB = (j1 < m) ? 1.f / H[j1 * HST + j1] : 0.f;
      for (int kk = 0; kk < m - 1; kk++) {
        float psrc = (kk < 64) ? __shfl(pA, kk, 64) : __shfl(pB, kk - 64, 64);
        float dsrc = (kk < 64) ? __shfl(dA, kk, 64) : __shfl(dB, kk - 64, 64);
        float zk = psrc * dsrc;
        if (l > kk && l < m)   pA -= H[l * HST + kk] * zk;
        if (j1 > kk && j1 < m) pB -= H[j1 * HST + kk] * zk;
      }
      pA *= dA; pB *= dB;
      for (int kk = m - 1; kk >= 1; kk--) {
        float pk = (kk < 64) ? __shfl(pA, kk, 64) : __shfl(pB, kk - 64, 64);
        if (l < kk)  pA -= H[kk * HST + l]  * dA * pk;
        if (j1 < kk) pB -= H[kk * HST + j1] * dB * pk;
      }
      if (l < m)  pv[l] = pA;
      if (j1 < m) pv[j1] = pB;
      // fused gtp + pmax reduction in-wave
      double gtpw = 0.0, pmw = 0.0;
      if (l < m)  { gtpw += (double)gv[l]  * (double)pA; double a = fabs((double)pA); if (a > pmw) pmw = a; }
      if (j1 < m) { gtpw += (double)gv[j1] * (double)pB; double a = fabs((double)pB); if (a > pmw) pmw = a; }
#pragma unroll
      for (int o2 = 32; o2 > 0; o2 >>= 1) {
        gtpw += __shfl_down(gtpw, o2, 64);
        double u = __shfl_down(pmw, o2, 64);
        pmw = fmax(pmw, u);
      }
      if (l == 0) { red[8] = gtpw; red[9] = pmw; }
    }
    __syncthreads();
    double gtp = red[8], pmax = red[9];
    if (!(gtp < 0.0)) { done = true; break; }  // converged/degenerate; Av/Sv valid

    float t = 1.f;
    if (-gtp >= 1e-4) {
      // ---- B_i = dot(K row i, pv) ; Armijo ----
      for (int i = tid; i < n; i += 256) {
        const float* Kr = K + (size_t)i * st + c0;
        float bsum = 0.f;
        int j = 0;
        for (; j + 7 < m; j += 8)
          bsum += pv[j] * Kr[j] + pv[j + 1] * Kr[j + 1] + pv[j + 2] * Kr[j + 2] + pv[j + 3] * Kr[j + 3]
                + pv[j + 4] * Kr[j + 4] + pv[j + 5] * Kr[j + 5] + pv[j + 6] * Kr[j + 6] + pv[j + 7] * Kr[j + 7];
        for (; j < m; j++) bsum += pv[j] * Kr[j];
        Bv[i] = bsum;
      }
      for (int ls = 0; ls < 10; ls++) {
        double ol = 0.0;
        for (int i = tid; i < n; i += 256)
          ol += (double)(gamma * expf(fminf(Av[i] + t * Bv[i] - 1.f, 30.f)));
        for (int j = tid; j < m; j += 256) {
          float tj = th[j] + t * pv[j];
          ol += (double)(-bc[j] * tj + LAMBDA * tj * tj);
        }
        double ot = blockReduceSum(ol, red);
        if (ot <= obj + 1e-4 * (double)t * gtp) break;
        t *= 0.5f;
      }
      if (t < 1.f) forceF = true;   // H stale or far phase: refactor next iter
    }
    for (int j = tid; j < m; j += 256) th[j] += t * pv[j];
    __syncthreads();
    if ((double)t * pmax < 1e-7) break;   // step negligible; recompute path below
  }

  if (!done) {
    // recompute Av/Sv for the final theta
    for (int i = tid; i < n; i += 256) {
      const float* Kr = K + (size_t)i * st + c0;
      float a = 0.f;
      for (int j = 0; j < m; j++) a += th[j] * Kr[j];
      Av[i] = a;
    }
    __syncthreads();
    for (int i = tid; i < n; i += 256) Sv[i] = gamma * expf(fminf(Av[i] - 1.f, 30.f));
    __syncthreads();
  }
  double t1l = 0.0, t2l = 0.0;
  for (int i = tid; i < n; i += 256) t2l += (double)Sv[i];
  for (int j = tid; j < m; j += 256) t1l += (double)(bc[j] * th[j]);
  double t1 = blockReduceSum(t1l, red);
  double t2 = blockReduceSum(t2l, red);
  if (tid == 0) {
    atomicAdd(&acc[0], t1);
    atomicAdd(&acc[1], t2);
  }
}

__global__ void final_k(const double* __restrict__ acc, float* __restrict__ out) {
  out[0] = (float)(acc[0] - acc[1]);
}

// ---------------- launcher ----------------
extern "C" void kernel_launch(void* const* d_in, const int* in_sizes, int n_in,
                              void* d_out, int out_size, void* d_ws, size_t ws_size,
                              hipStream_t stream) {
  const float* sf = (const float*)d_in[0];
  const float* tf = (const float*)d_in[1];
  const int* y = (const int*)d_in[2];
  const int* l = (const int*)d_in[3];
  char* ws = (char*)d_ws;

  double*   acc    = (double*)(ws + WS_ACC);
  unsigned* hist0  = (unsigned*)(ws + WS_HIST0);
  unsigned* histA  = (unsigned*)(ws + WS_HISTA);
  unsigned* histB  = (unsigned*)(ws + WS_HISTB);
  unsigned* h2A    = (unsigned*)(ws + WS_H2A);
  unsigned* h2B    = (unsigned*)(ws + WS_H2B);
  unsigned* state  = (unsigned*)(ws + WS_STATE);
  unsigned* cnt    = (unsigned*)(ws + WS_CNT);
  unsigned* cnt2   = (unsigned*)(ws + WS_CNT2);
  unsigned* bstart = (unsigned*)(ws + WS_BSTART);
  int*      meta   = (int*)(ws + WS_META);
  float*    scal   = (float*)(ws + WS_SCAL);
  int*      perm   = (int*)(ws + WS_PERM);
  float*    xnp    = (float*)(ws + WS_XN);
  float*    Ds     = (float*)(ws + WS_DS);
  float*    gK     = (float*)(ws + WS_KBLK);

  hipMemsetAsync(d_ws, 0, ZERO_BYTES, stream);
  hipLaunchKernelGGL(xn_kernel, dim3(1024), dim3(256), 0, stream, sf, tf, xnp);
  hipLaunchKernelGGL(dist_k, dim3(32, 32), dim3(16, 16), 0, stream, sf, xnp, Ds);
  hipLaunchKernelGGL(hist0_k, dim3(512), dim3(256), 0, stream, Ds, hist0);
  hipLaunchKernelGGL(scan0_k, dim3(1), dim3(256), 0, stream, hist0, state);
  hipLaunchKernelGGL(hist1_k, dim3(512), dim3(256), 0, stream, Ds, state, histA, histB);
  hipLaunchKernelGGL(scan1_k, dim3(1), dim3(256), 0, stream, histA, histB, state);
  hipLaunchKernelGGL(hist2_k, dim3(512), dim3(256), 0, stream, Ds, state, h2A, h2B);
  hipLaunchKernelGGL(scan2_k, dim3(1), dim3(256), 0, stream, h2A, h2B, state, scal);
  hipLaunchKernelGGL(cnt_k, dim3(16), dim3(256), 0, stream, y, l, cnt);
  hipLaunchKernelGGL(scank_k, dim3(1), dim3(1), 0, stream, cnt, bstart, meta, scal);
  hipLaunchKernelGGL(scat_k, dim3(16), dim3(256), 0, stream, y, l, bstart, cnt2, perm);
  hipLaunchKernelGGL(build_k, dim3(16, 16, NCLASS), dim3(16, 16), 0, stream, sf, tf, xnp, perm, meta, scal, gK);
  hipLaunchKernelGGL(solver_k, dim3(62), dim3(256), 0, stream, gK, meta, scal, acc);
  hipLaunchKernelGGL(final_k, dim3(1), dim3(1), 0, stream, acc, (float*)d_out);
}

// Round 5
// 299.145 us; speedup vs baseline: 13.0910x; 2.8554x over previous
//
#include <hip/hip_runtime.h>
#include <math.h>

#define N_TOT   4096
#define N_SRC   2048
#define DIMF    256
#define NCLASS  31
#define LAMBDA  0.01f

// median target ranks (0-indexed) among 4192256 non-NaN values
#define K_MED1  2096127LL
#define K_MED2  2096128LL

// ---- ws layout (bytes) ----
#define WS_ACC    0           // 2 doubles
#define WS_HIST0  64          // 4096 u32
#define WS_HISTA  16448       // 4096 u32
#define WS_HISTB  32832       // 4096 u32
#define WS_H2A    49216       // 256 u32
#define WS_H2B    50240       // 256 u32
#define WS_STATE  51264       // 64 u32
#define WS_CNT    51520       // 64 u32
#define WS_CNT2   51776       // 64 u32
#define WS_BSTART 52032       // 64 u32
#define WS_META   52288       // 128 i32: ncls[32], m0c[32], cstart[32], blkoff[32]
#define WS_SCAL   52800       // 16 f32: [0]=sigma, [1]=gamma0, [2]=gamma1
#define ZERO_BYTES 53248
#define WS_PERM   53248       // 4096 i32
#define WS_XN     69632       // 4096 f32
#define WS_DS     1048576     // 2048*2048 f32 (16.78 MB)
#define WS_KBLK   17825792    // class K blocks (8 MB budget)

// solver capacity: class size n ~ Binom(4096,1/31): mean 132, sd 11.3 -> MAXW=224 is +8.1 sigma
// per-(class,domain) m ~ mean 66, sd 8 -> MAXM=112 is +5.7 sigma
#define MAXW 224
#define MAXM 112
#define WPAD 114   // u16 row stride = 57 dwords (odd -> conflict-free rows & cols)

__device__ __forceinline__ float bf2f(unsigned short h) {
  return __uint_as_float(((unsigned)h) << 16);
}

// ---------------- reductions ----------------
__device__ __forceinline__ double blockReduceSum(double v, double* red) {
#pragma unroll
  for (int o = 32; o > 0; o >>= 1) v += __shfl_down(v, o, 64);
  int w = threadIdx.x >> 6, lane = threadIdx.x & 63;
  __syncthreads();
  if (lane == 0) red[w] = v;
  __syncthreads();
  return red[0] + red[1] + red[2] + red[3];
}

__device__ __forceinline__ void blockReduceSumMax(double s, double mx, double* red,
                                                  double& os, double& om) {
#pragma unroll
  for (int o = 32; o > 0; o >>= 1) {
    s += __shfl_down(s, o, 64);
    double u = __shfl_down(mx, o, 64);
    mx = fmax(mx, u);
  }
  int w = threadIdx.x >> 6, lane = threadIdx.x & 63;
  __syncthreads();
  if (lane == 0) { red[w] = s; red[4 + w] = mx; }
  __syncthreads();
  os = red[0] + red[1] + red[2] + red[3];
  om = fmax(fmax(red[4], red[5]), fmax(red[6], red[7]));
}

// ---------------- row norms ----------------
__global__ __launch_bounds__(256) void xn_kernel(const float* __restrict__ sf,
                                                 const float* __restrict__ tf,
                                                 float* __restrict__ xn) {
  int wid = threadIdx.x >> 6, lane = threadIdx.x & 63;
  int row = blockIdx.x * 4 + wid;
  const float* src = (row < N_SRC) ? (sf + (size_t)row * DIMF) : (tf + (size_t)(row - N_SRC) * DIMF);
  float4 v = ((const float4*)src)[lane];
  float s = v.x * v.x + v.y * v.y + v.z * v.z + v.w * v.w;
#pragma unroll
  for (int o = 32; o > 0; o >>= 1) s += __shfl_down(s, o, 64);
  if (lane == 0) xn[row] = s;
}

// ---------------- source pairwise sq-dists (for median) ----------------
__global__ __launch_bounds__(256) void dist_k(const float* __restrict__ sf,
                                              const float* __restrict__ xn,
                                              float* __restrict__ Ds) {
  __shared__ float As[16][68];
  __shared__ float Bs[16][68];
  const int tx = threadIdx.x, ty = threadIdx.y;
  const int tid = ty * 16 + tx;
  const int R = blockIdx.y * 64, C = blockIdx.x * 64;
  float acc[4][4] = {};
  for (int kc = 0; kc < 256; kc += 16) {
    int i = tid >> 2, q = tid & 3;
    float4 va = ((const float4*)(sf + (size_t)(R + i) * 256 + kc))[q];
    As[q * 4 + 0][i] = va.x; As[q * 4 + 1][i] = va.y; As[q * 4 + 2][i] = va.z; As[q * 4 + 3][i] = va.w;
    float4 vb = ((const float4*)(sf + (size_t)(C + i) * 256 + kc))[q];
    Bs[q * 4 + 0][i] = vb.x; Bs[q * 4 + 1][i] = vb.y; Bs[q * 4 + 2][i] = vb.z; Bs[q * 4 + 3][i] = vb.w;
    __syncthreads();
#pragma unroll
    for (int k = 0; k < 16; k++) {
      float4 a = *(const float4*)&As[k][ty * 4];
      float4 b = *(const float4*)&Bs[k][tx * 4];
      acc[0][0] += a.x * b.x; acc[0][1] += a.x * b.y; acc[0][2] += a.x * b.z; acc[0][3] += a.x * b.w;
      acc[1][0] += a.y * b.x; acc[1][1] += a.y * b.y; acc[1][2] += a.y * b.z; acc[1][3] += a.y * b.w;
      acc[2][0] += a.z * b.x; acc[2][1] += a.z * b.y; acc[2][2] += a.z * b.z; acc[2][3] += a.z * b.w;
      acc[3][0] += a.w * b.x; acc[3][1] += a.w * b.y; acc[3][2] += a.w * b.z; acc[3][3] += a.w * b.w;
    }
    __syncthreads();
  }
  const float INF = __int_as_float(0x7f800000);
  int jbase = C + tx * 4;
  float xnj0 = xn[jbase + 0], xnj1 = xn[jbase + 1], xnj2 = xn[jbase + 2], xnj3 = xn[jbase + 3];
#pragma unroll
  for (int r = 0; r < 4; r++) {
    int i = R + ty * 4 + r;
    float xni = xn[i];
    float4 o;
    o.x = fmaxf(xni + xnj0 - 2.f * acc[r][0], 0.f);
    o.y = fmaxf(xni + xnj1 - 2.f * acc[r][1], 0.f);
    o.z = fmaxf(xni + xnj2 - 2.f * acc[r][2], 0.f);
    o.w = fmaxf(xni + xnj3 - 2.f * acc[r][3], 0.f);
    if (i == jbase + 0) o.x = INF;
    if (i == jbase + 1) o.y = INF;
    if (i == jbase + 2) o.z = INF;
    if (i == jbase + 3) o.w = INF;
    ((float4*)&Ds[(size_t)i * 2048 + jbase])[0] = o;
  }
}

// ---------------- radix-select median (3 passes) ----------------
__global__ __launch_bounds__(256) void hist0_k(const float* __restrict__ Ds, unsigned* __restrict__ h) {
  __shared__ unsigned lh[4096];
  for (int i = threadIdx.x; i < 4096; i += 256) lh[i] = 0;
  __syncthreads();
  unsigned total = 2048u * 2048u;
  for (unsigned idx = blockIdx.x * 256 + threadIdx.x; idx < total; idx += gridDim.x * 256) {
    unsigned u = __float_as_uint(Ds[idx]);
    atomicAdd(&lh[u >> 20], 1u);
  }
  __syncthreads();
  for (int i = threadIdx.x; i < 4096; i += 256) if (lh[i]) atomicAdd(&h[i], lh[i]);
}

__global__ __launch_bounds__(256) void hist1_k(const float* __restrict__ Ds, const unsigned* __restrict__ st,
                                               unsigned* __restrict__ hA, unsigned* __restrict__ hB) {
  __shared__ unsigned lA[4096];
  __shared__ unsigned lB[4096];
  for (int i = threadIdx.x; i < 4096; i += 256) { lA[i] = 0; lB[i] = 0; }
  __syncthreads();
  unsigned s0 = st[0], s1 = st[2];
  unsigned total = 2048u * 2048u;
  for (unsigned idx = blockIdx.x * 256 + threadIdx.x; idx < total; idx += gridDim.x * 256) {
    unsigned u = __float_as_uint(Ds[idx]);
    unsigned hi = u >> 20, mid = (u >> 8) & 0xFFFu;
    if (hi == s0) atomicAdd(&lA[mid], 1u);
    if (hi == s1) atomicAdd(&lB[mid], 1u);
  }
  __syncthreads();
  for (int i = threadIdx.x; i < 4096; i += 256) {
    if (lA[i]) atomicAdd(&hA[i], lA[i]);
    if (lB[i]) atomicAdd(&hB[i], lB[i]);
  }
}

__global__ __launch_bounds__(256) void hist2_k(const float* __restrict__ Ds, const unsigned* __restrict__ st,
                                               unsigned* __restrict__ hA, unsigned* __restrict__ hB) {
  __shared__ unsigned lA[256];
  __shared__ unsigned lB[256];
  if (threadIdx.x < 256) { lA[threadIdx.x] = 0; lB[threadIdx.x] = 0; }
  __syncthreads();
  unsigned p0 = (st[0] << 12) | st[4];
  unsigned p1 = (st[2] << 12) | st[6];
  unsigned total = 2048u * 2048u;
  for (unsigned idx = blockIdx.x * 256 + threadIdx.x; idx < total; idx += gridDim.x * 256) {
    unsigned u = __float_as_uint(Ds[idx]);
    unsigned pre = u >> 8;
    if (pre == p0) atomicAdd(&lA[u & 0xFFu], 1u);
    if (pre == p1) atomicAdd(&lB[u & 0xFFu], 1u);
  }
  __syncthreads();
  if (lA[threadIdx.x]) atomicAdd(&hA[threadIdx.x], lA[threadIdx.x]);
  if (lB[threadIdx.x]) atomicAdd(&hB[threadIdx.x], lB[threadIdx.x]);
}

__device__ void scan_find(const unsigned* hist, int nbins, long long k, unsigned* shOut) {
  __shared__ long long tsum[256];
  int per = nbins / 256;
  long long s = 0;
  for (int q = 0; q < per; q++) s += hist[threadIdx.x * per + q];
  tsum[threadIdx.x] = s;
  __syncthreads();
  if (threadIdx.x == 0) {
    long long run = 0;
    for (int t = 0; t < 256; t++) { long long v = tsum[t]; tsum[t] = run; run += v; }
  }
  __syncthreads();
  long long run = tsum[threadIdx.x];
  for (int q = 0; q < per; q++) {
    unsigned c = hist[threadIdx.x * per + q];
    if (k >= run && k < run + (long long)c) { shOut[0] = (unsigned)(threadIdx.x * per + q); shOut[1] = (unsigned)(k - run); }
    run += c;
  }
  __syncthreads();
}

__global__ __launch_bounds__(256) void scan0_k(const unsigned* __restrict__ h, unsigned* __restrict__ st) {
  __shared__ unsigned r0[2];
  __shared__ unsigned r1[2];
  scan_find(h, 4096, K_MED1, r0);
  scan_find(h, 4096, K_MED2, r1);
  if (threadIdx.x == 0) { st[0] = r0[0]; st[1] = r0[1]; st[2] = r1[0]; st[3] = r1[1]; }
}

__global__ __launch_bounds__(256) void scan1_k(const unsigned* __restrict__ hA, const unsigned* __restrict__ hB,
                                               unsigned* __restrict__ st) {
  __shared__ unsigned r0[2];
  __shared__ unsigned r1[2];
  long long kA = (long long)st[1];
  long long kB = (long long)st[3];
  scan_find(hA, 4096, kA, r0);
  scan_find(hB, 4096, kB, r1);
  if (threadIdx.x == 0) { st[4] = r0[0]; st[5] = r0[1]; st[6] = r1[0]; st[7] = r1[1]; }
}

__global__ __launch_bounds__(256) void scan2_k(const unsigned* __restrict__ hA, const unsigned* __restrict__ hB,
                                               unsigned* __restrict__ st, float* __restrict__ scal) {
  __shared__ unsigned r0[2];
  __shared__ unsigned r1[2];
  long long kA = (long long)st[5];
  long long kB = (long long)st[7];
  scan_find(hA, 256, kA, r0);
  scan_find(hB, 256, kB, r1);
  if (threadIdx.x == 0) {
    unsigned v1 = (st[0] << 20) | (st[4] << 8) | r0[0];
    unsigned v2 = (st[2] << 20) | (st[6] << 8) | r1[0];
    scal[0] = 0.5f * (__uint_as_float(v1) + __uint_as_float(v2));  // sigma
  }
}

// ---------------- class/domain bucketing ----------------
__global__ void cnt_k(const int* __restrict__ y, const int* __restrict__ l, unsigned* __restrict__ cnt) {
  int i = blockIdx.x * 256 + threadIdx.x;
  if (i < N_TOT) atomicAdd(&cnt[y[i] * 2 + l[i]], 1u);
}

__global__ void scank_k(const unsigned* __restrict__ cnt, unsigned* __restrict__ bstart,
                        int* __restrict__ meta, float* __restrict__ scal) {
  unsigned run = 0;
  for (int b = 0; b < 62; b++) { bstart[b] = run; run += cnt[b]; }
  int* ncls = meta; int* m0c = meta + 32; int* cstart = meta + 64; int* blkoff = meta + 96;
  unsigned run2 = 0, cnt0 = 0;
  for (int c = 0; c < NCLASS; c++) {
    int n = (int)(cnt[2 * c] + cnt[2 * c + 1]);
    ncls[c] = n; m0c[c] = (int)cnt[2 * c]; cstart[c] = (int)bstart[2 * c];
    blkoff[c] = (int)run2; run2 += (unsigned)(n * n);
    cnt0 += cnt[2 * c];
  }
  scal[1] = (float)((double)cnt0 / (4096.0 * 4096.0));
  scal[2] = (float)((double)(N_TOT - cnt0) / (4096.0 * 4096.0));
}

__global__ void scat_k(const int* __restrict__ y, const int* __restrict__ l,
                       const unsigned* __restrict__ bstart, unsigned* __restrict__ cnt2,
                       int* __restrict__ perm) {
  int i = blockIdx.x * 256 + threadIdx.x;
  if (i < N_TOT) {
    int b = y[i] * 2 + l[i];
    unsigned pos = bstart[b] + atomicAdd(&cnt2[b], 1u);
    perm[pos] = i;
  }
}

// ---------------- build per-class K blocks ----------------
__global__ __launch_bounds__(256) void build_k(const float* __restrict__ sf, const float* __restrict__ tf,
                                               const float* __restrict__ xn, const int* __restrict__ perm,
                                               const int* __restrict__ meta, const float* __restrict__ scal,
                                               float* __restrict__ gK) {
  const int c = blockIdx.z;
  const int n = meta[c];
  const int cs = meta[64 + c];
  const int bo = meta[96 + c];
  const int tx = threadIdx.x, ty = threadIdx.y;
  const int i0 = blockIdx.y * 16, j0 = blockIdx.x * 16;
  if (i0 >= n || j0 >= n) return;
  __shared__ float As[16][260];
  __shared__ float Bs[16][260];
  __shared__ int ra[16];
  __shared__ int rb[16];
  int tid = ty * 16 + tx;
  if (tid < 16) { int il = i0 + tid; ra[tid] = (il < n) ? perm[cs + il] : -1; }
  else if (tid < 32) { int jl = j0 + tid - 16; rb[tid - 16] = (jl < n) ? perm[cs + jl] : -1; }
  __syncthreads();
  for (int e = tid; e < 1024; e += 256) {
    int r = e >> 6, q = e & 63;
    int g = ra[r];
    if (g >= 0) {
      const float* src = (g < N_SRC) ? (sf + (size_t)g * DIMF) : (tf + (size_t)(g - N_SRC) * DIMF);
      ((float4*)&As[r][q * 4])[0] = ((const float4*)src)[q];
    }
    int g2 = rb[r];
    if (g2 >= 0) {
      const float* src = (g2 < N_SRC) ? (sf + (size_t)g2 * DIMF) : (tf + (size_t)(g2 - N_SRC) * DIMF);
      ((float4*)&Bs[r][q * 4])[0] = ((const float4*)src)[q];
    }
  }
  __syncthreads();
  int il = i0 + ty, jl = j0 + tx;
  if (il < n && jl < n) {
    float dot = 0.f;
    const float4* a4 = (const float4*)&As[ty][0];
    const float4* b4 = (const float4*)&Bs[tx][0];
#pragma unroll 16
    for (int q = 0; q < 64; q++) {
      float4 a = a4[q], b = b4[q];
      dot += a.x * b.x + a.y * b.y + a.z * b.z + a.w * b.w;
    }
    int gi = ra[ty], gj = rb[tx];
    float d = xn[gi] + xn[gj] - 2.f * dot;
    gK[(size_t)bo + (size_t)il * n + jl] = expf(-d / scal[0]);
  }
}

// ---------------- per-(class,domain) Newton-PCG ----------------
// R5: K~ staged in LDS as bf16 (stride 57 dwords, conflict-free both ways).
// Exact Hessian applied matrix-free: Hv = W^T diag(S) (W v) + 2*lambda*v,
// Jacobi-preconditioned CG (kappa ~ 2-3). No stored H, no factorization.
// Final term1/term2 always recomputed from f32 global K with f32 theta.
__global__ __launch_bounds__(256) void solver_k(const float* __restrict__ gK, const int* __restrict__ meta,
                                                const float* __restrict__ scal, double* __restrict__ acc) {
  const int c = blockIdx.x >> 1, d = blockIdx.x & 1;
  const int n = meta[c];
  const int m0 = meta[32 + c];
  const int m = d ? (n - m0) : m0;
  const int c0 = d ? m0 : 0;
  const int bo = meta[96 + c];
  const float gamma = scal[1 + d];
  const int tid = threadIdx.x;

  __shared__ unsigned short Wl[MAXW * WPAD];   // 51072 B
  __shared__ float Av[MAXW];
  __shared__ float Sv[MAXW];
  __shared__ float Uv[MAXW];
  __shared__ float Bq[MAXW];    // q (m) then Bv (n) for line search
  __shared__ float bc[MAXM];
  __shared__ float th[MAXM + 1];
  __shared__ float gv[MAXM];
  __shared__ float dgv[MAXM];
  __shared__ float pv[MAXM + 1];
  __shared__ float rv[MAXM + 1];
  __shared__ float zv[MAXM + 1];
  __shared__ float xv[MAXM + 1];
  __shared__ double red[16];

  const float* K = gK + bo;
  const int st = n;
  const int mp2 = (m + 1) & ~1;   // pair-aligned column count

  // ---- stage W = bf16(K[:, c0:c0+m]), zero the pad column ----
  for (int i = tid >> 2; i < n; i += 64) {
    const float* Kr = K + (size_t)i * st + c0;
    unsigned short* Wr = Wl + i * WPAD;
    for (int j = (tid & 3); j < m; j += 4) {
      unsigned u = __float_as_uint(Kr[j]);
      u += 0x7fffu + ((u >> 16) & 1u);   // RNE to bf16
      Wr[j] = (unsigned short)(u >> 16);
    }
    if ((tid & 3) == 0 && (m & 1)) Wr[m] = 0;
  }
  // ---- bc (exact f32) + theta init (incl pad slot) ----
  for (int j = tid; j < mp2; j += 256) {
    float sum = 0.f;
    if (j < m) {
      const float* Kr = K + (size_t)(c0 + j) * st + c0;
      int r = 0;
      for (; r + 7 < m; r += 8)
        sum += Kr[r] + Kr[r+1] + Kr[r+2] + Kr[r+3] + Kr[r+4] + Kr[r+5] + Kr[r+6] + Kr[r+7];
      for (; r < m; r++) sum += Kr[r];
      bc[j] = sum * (1.0f / 4096.0f);
    }
    th[j] = 0.f;
  }
  __syncthreads();

  for (int it = 0; it < 25; it++) {
    // ---- Av = W th (row matvec, LDS) ----
    for (int i = tid; i < n; i += 256) {
      const unsigned short* Wr = Wl + i * WPAD;
      float a = 0.f;
#pragma unroll 4
      for (int j = 0; j < mp2; j += 2) {
        unsigned u = *(const unsigned*)(Wr + j);
        a += __uint_as_float(u << 16) * th[j]
           + __uint_as_float(u & 0xffff0000u) * th[j + 1];
      }
      Av[i] = a;
    }
    __syncthreads();
    // ---- S, obj ----
    double o = 0.0;
    for (int i = tid; i < n; i += 256) {
      float si = gamma * expf(fminf(Av[i] - 1.f, 30.f));
      Sv[i] = si; o += (double)si;
    }
    for (int j = tid; j < m; j += 256) {
      float t_ = th[j];
      o += (double)(-bc[j] * t_ + LAMBDA * t_ * t_);
    }
    __syncthreads();
    // ---- gradient + Jacobi diag (column matvec, LDS) ----
    double gm = 0.0;
    for (int j = tid; j < m; j += 256) {
      const unsigned short* Wc = Wl + j;
      float s_ = 0.f, ds_ = 0.f;
      int i = 0;
      for (; i + 3 < n; i += 4) {
        float w0 = bf2f(Wc[(i + 0) * WPAD]), w1 = bf2f(Wc[(i + 1) * WPAD]);
        float w2 = bf2f(Wc[(i + 2) * WPAD]), w3 = bf2f(Wc[(i + 3) * WPAD]);
        float a0 = w0 * Sv[i], a1 = w1 * Sv[i + 1], a2 = w2 * Sv[i + 2], a3 = w3 * Sv[i + 3];
        s_ += a0 + a1 + a2 + a3;
        ds_ += a0 * w0 + a1 * w1 + a2 * w2 + a3 * w3;
      }
      for (; i < n; i++) { float w = bf2f(Wc[i * WPAD]); float a = w * Sv[i]; s_ += a; ds_ += a * w; }
      float g = s_ - bc[j] + 2.f * LAMBDA * th[j];
      gv[j] = g;
      dgv[j] = ds_ + 2.f * LAMBDA;
      double ag = fabs((double)g); if (ag > gm) gm = ag;
    }
    double obj, gmax;
    blockReduceSumMax(o, gm, red, obj, gmax);
    if (gmax < 1e-5) break;

    // ---- PCG solve H x = -g (Jacobi precond), x0 = 0 ----
    double rz = 0.0;
    for (int j = tid; j < mp2; j += 256) {
      float r0 = (j < m) ? -gv[j] : 0.f;
      float z0 = (j < m) ? r0 / dgv[j] : 0.f;
      rv[j] = r0; zv[j] = z0; pv[j] = z0; xv[j] = 0.f;
      rz += (double)r0 * (double)z0;
    }
    rz = blockReduceSum(rz, red);
    double rz0 = rz;
    for (int cg = 0; cg < 12; cg++) {
      __syncthreads();  // pv visible
      // u = S .* (W p)
      for (int i = tid; i < n; i += 256) {
        const unsigned short* Wr = Wl + i * WPAD;
        float a = 0.f;
#pragma unroll 4
        for (int j = 0; j < mp2; j += 2) {
          unsigned u = *(const unsigned*)(Wr + j);
          a += __uint_as_float(u << 16) * pv[j]
             + __uint_as_float(u & 0xffff0000u) * pv[j + 1];
        }
        Uv[i] = a * Sv[i];
      }
      __syncthreads();
      // q = W^T u + 2*lambda*p ; pq
      double pq = 0.0;
      for (int j = tid; j < m; j += 256) {
        const unsigned short* Wc = Wl + j;
        float q = 0.f;
        int i = 0;
        for (; i + 3 < n; i += 4)
          q += bf2f(Wc[(i+0)*WPAD]) * Uv[i]   + bf2f(Wc[(i+1)*WPAD]) * Uv[i+1]
             + bf2f(Wc[(i+2)*WPAD]) * Uv[i+2] + bf2f(Wc[(i+3)*WPAD]) * Uv[i+3];
        for (; i < n; i++) q += bf2f(Wc[i * WPAD]) * Uv[i];
        q += 2.f * LAMBDA * pv[j];
        Bq[j] = q;
        pq += (double)pv[j] * (double)q;
      }
      pq = blockReduceSum(pq, red);
      if (!(pq > 0.0)) break;
      float alpha = (float)(rz / pq);
      double rznew = 0.0;
      for (int j = tid; j < m; j += 256) {
        xv[j] += alpha * pv[j];
        float rn = rv[j] - alpha * Bq[j];
        rv[j] = rn;
        float zn = rn / dgv[j];
        zv[j] = zn;
        rznew += (double)rn * (double)zn;
      }
      rznew = blockReduceSum(rznew, red);
      if (rznew < 1e-4 * rz0 || cg == 11) break;
      float beta = (float)(rznew / rz);
      for (int j = tid; j < m; j += 256) pv[j] = zv[j] + beta * pv[j];
      rz = rznew;
    }
    __syncthreads();
    // ---- direction d = xv ; gtp ; pmax ----
    double gtpl = 0.0, pml = 0.0;
    for (int j = tid; j < m; j += 256) {
      gtpl += (double)gv[j] * (double)xv[j];
      double ax = fabs((double)xv[j]); if (ax > pml) pml = ax;
    }
    double gtp, pmax;
    blockReduceSumMax(gtpl, pml, red, gtp, pmax);
    if (!(gtp < 0.0)) break;

    float t = 1.f;
    if (-gtp >= 1e-4) {
      // Bv = W d (row matvec) + Armijo
      for (int i = tid; i < n; i += 256) {
        const unsigned short* Wr = Wl + i * WPAD;
        float a = 0.f;
#pragma unroll 4
        for (int j = 0; j < mp2; j += 2) {
          unsigned u = *(const unsigned*)(Wr + j);
          a += __uint_as_float(u << 16) * xv[j]
             + __uint_as_float(u & 0xffff0000u) * xv[j + 1];
        }
        Bq[i] = a;
      }
      __syncthreads();
      for (int ls = 0; ls < 10; ls++) {
        double ol = 0.0;
        for (int i = tid; i < n; i += 256)
          ol += (double)(gamma * expf(fminf(Av[i] + t * Bq[i] - 1.f, 30.f)));
        for (int j = tid; j < m; j += 256) {
          float tj = th[j] + t * xv[j];
          ol += (double)(-bc[j] * tj + LAMBDA * tj * tj);
        }
        double ot = blockReduceSum(ol, red);
        if (ot <= obj + 1e-4 * (double)t * gtp) break;
        t *= 0.5f;
      }
    }
    for (int j = tid; j < mp2; j += 256) th[j] += t * xv[j];
    __syncthreads();
    if ((double)t * pmax < 1e-7) break;
  }

  // ---- final exact f32 evaluation (global K, f32 theta) ----
  __syncthreads();
  for (int i = tid; i < n; i += 256) {
    const float* Kr = K + (size_t)i * st + c0;
    float a = 0.f;
    int j = 0;
    for (; j + 7 < m; j += 8)
      a += th[j] * Kr[j] + th[j+1] * Kr[j+1] + th[j+2] * Kr[j+2] + th[j+3] * Kr[j+3]
         + th[j+4] * Kr[j+4] + th[j+5] * Kr[j+5] + th[j+6] * Kr[j+6] + th[j+7] * Kr[j+7];
    for (; j < m; j++) a += th[j] * Kr[j];
    Av[i] = a;
  }
  __syncthreads();
  double t1l = 0.0, t2l = 0.0;
  for (int i = tid; i < n; i += 256) t2l += (double)(gamma * expf(fminf(Av[i] - 1.f, 30.f)));
  for (int j = tid; j < m; j += 256) t1l += (double)(bc[j] * th[j]);
  double t1 = blockReduceSum(t1l, red);
  double t2 = blockReduceSum(t2l, red);
  if (tid == 0) {
    atomicAdd(&acc[0], t1);
    atomicAdd(&acc[1], t2);
  }
}

__global__ void final_k(const double* __restrict__ acc, float* __restrict__ out) {
  out[0] = (float)(acc[0] - acc[1]);
}

// ---------------- launcher ----------------
extern "C" void kernel_launch(void* const* d_in, const int* in_sizes, int n_in,
                              void* d_out, int out_size, void* d_ws, size_t ws_size,
                              hipStream_t stream) {
  const float* sf = (const float*)d_in[0];
  const float* tf = (const float*)d_in[1];
  const int* y = (const int*)d_in[2];
  const int* l = (const int*)d_in[3];
  char* ws = (char*)d_ws;

  double*   acc    = (double*)(ws + WS_ACC);
  unsigned* hist0  = (unsigned*)(ws + WS_HIST0);
  unsigned* histA  = (unsigned*)(ws + WS_HISTA);
  unsigned* histB  = (unsigned*)(ws + WS_HISTB);
  unsigned* h2A    = (unsigned*)(ws + WS_H2A);
  unsigned* h2B    = (unsigned*)(ws + WS_H2B);
  unsigned* state  = (unsigned*)(ws + WS_STATE);
  unsigned* cnt    = (unsigned*)(ws + WS_CNT);
  unsigned* cnt2   = (unsigned*)(ws + WS_CNT2);
  unsigned* bstart = (unsigned*)(ws + WS_BSTART);
  int*      meta   = (int*)(ws + WS_META);
  float*    scal   = (float*)(ws + WS_SCAL);
  int*      perm   = (int*)(ws + WS_PERM);
  float*    xnp    = (float*)(ws + WS_XN);
  float*    Ds     = (float*)(ws + WS_DS);
  float*    gK     = (float*)(ws + WS_KBLK);

  hipMemsetAsync(d_ws, 0, ZERO_BYTES, stream);
  hipLaunchKernelGGL(xn_kernel, dim3(1024), dim3(256), 0, stream, sf, tf, xnp);
  hipLaunchKernelGGL(dist_k, dim3(32, 32), dim3(16, 16), 0, stream, sf, xnp, Ds);
  hipLaunchKernelGGL(hist0_k, dim3(512), dim3(256), 0, stream, Ds, hist0);
  hipLaunchKernelGGL(scan0_k, dim3(1), dim3(256), 0, stream, hist0, state);
  hipLaunchKernelGGL(hist1_k, dim3(512), dim3(256), 0, stream, Ds, state, histA, histB);
  hipLaunchKernelGGL(scan1_k, dim3(1), dim3(256), 0, stream, histA, histB, state);
  hipLaunchKernelGGL(hist2_k, dim3(512), dim3(256), 0, stream, Ds, state, h2A, h2B);
  hipLaunchKernelGGL(scan2_k, dim3(1), dim3(256), 0, stream, h2A, h2B, state, scal);
  hipLaunchKernelGGL(cnt_k, dim3(16), dim3(256), 0, stream, y, l, cnt);
  hipLaunchKernelGGL(scank_k, dim3(1), dim3(1), 0, stream, cnt, bstart, meta, scal);
  hipLaunchKernelGGL(scat_k, dim3(16), dim3(256), 0, stream, y, l, bstart, cnt2, perm);
  hipLaunchKernelGGL(build_k, dim3(16, 16, NCLASS), dim3(16, 16), 0, stream, sf, tf, xnp, perm, meta, scal, gK);
  hipLaunchKernelGGL(solver_k, dim3(62), dim3(256), 0, stream, gK, meta, scal, acc);
  hipLaunchKernelGGL(final_k, dim3(1), dim3(1), 0, stream, acc, (float*)d_out);
}

// Round 6
// 258.346 us; speedup vs baseline: 15.1584x; 1.1579x over previous
//
#include <hip/hip_runtime.h>
#include <math.h>

#define N_TOT   4096
#define N_SRC   2048
#define DIMF    256
#define NCLASS  31
#define LAMBDA  0.01f

// median target ranks among the 2,096,128 strict-lower-triangle values.
// Full multiset = each triangle value twice -> full ranks {2096127,2096128}
// map to triangle ranks {1048063,1048064}.
#define K_TRI1  1048063LL
#define K_TRI2  1048064LL

// ---- ws layout (bytes) ----
#define WS_ACC    0           // 2 doubles
#define WS_HIST0  64          // 4096 u32
#define WS_HISTA  16448       // 4096 u32
#define WS_HISTB  32832       // 4096 u32
#define WS_H2A    49216       // 256 u32
#define WS_H2B    50240       // 256 u32
#define WS_STATE  51264       // 64 u32
#define WS_META   52288       // 128 i32: ncls[32], m0c[32], cstart[32], blkoff[32]
#define WS_SCAL   52800       // 16 f32: [0]=sigma, [1]=gamma0, [2]=gamma1
#define ZERO_BYTES 53248
#define WS_PERM   53248       // 4096 i32
#define WS_XN     69632       // 4096 f32
#define WS_DS     1048576     // 2048*2048 f32 (lower triangle used)
#define WS_KBLK   17825792    // class K blocks (8 MB budget)

// solver capacity: class size n ~ Binom(4096,1/31): mean 132, sd 11.3 -> MAXW=224 (+8.1 sigma)
// per-(class,domain) m ~ mean 66, sd 8 -> MAXM=112 (+5.7 sigma)
#define MAXW 224
#define MAXM 112
#define WPAD 114   // u16 row stride = 57 dwords (odd -> conflict-free rows & cols)

__device__ __forceinline__ float bf2f(unsigned short h) {
  return __uint_as_float(((unsigned)h) << 16);
}

// ---------------- reductions ----------------
__device__ __forceinline__ double blockReduceSum(double v, double* red) {
#pragma unroll
  for (int o = 32; o > 0; o >>= 1) v += __shfl_down(v, o, 64);
  int w = threadIdx.x >> 6, lane = threadIdx.x & 63;
  __syncthreads();
  if (lane == 0) red[w] = v;
  __syncthreads();
  return red[0] + red[1] + red[2] + red[3];
}

__device__ __forceinline__ void blockReduceSumMax(double s, double mx, double* red,
                                                  double& os, double& om) {
#pragma unroll
  for (int o = 32; o > 0; o >>= 1) {
    s += __shfl_down(s, o, 64);
    double u = __shfl_down(mx, o, 64);
    mx = fmax(mx, u);
  }
  int w = threadIdx.x >> 6, lane = threadIdx.x & 63;
  __syncthreads();
  if (lane == 0) { red[w] = s; red[4 + w] = mx; }
  __syncthreads();
  os = red[0] + red[1] + red[2] + red[3];
  om = fmax(fmax(red[4], red[5]), fmax(red[6], red[7]));
}

// ---------------- row norms ----------------
__global__ __launch_bounds__(256) void xn_kernel(const float* __restrict__ sf,
                                                 const float* __restrict__ tf,
                                                 float* __restrict__ xn) {
  int wid = threadIdx.x >> 6, lane = threadIdx.x & 63;
  int row = blockIdx.x * 4 + wid;
  const float* src = (row < N_SRC) ? (sf + (size_t)row * DIMF) : (tf + (size_t)(row - N_SRC) * DIMF);
  float4 v = ((const float4*)src)[lane];
  float s = v.x * v.x + v.y * v.y + v.z * v.z + v.w * v.w;
#pragma unroll
  for (int o = 32; o > 0; o >>= 1) s += __shfl_down(s, o, 64);
  if (lane == 0) xn[row] = s;
}

// ------- source pairwise sq-dists, lower triangle only, fused 12-bit hist -------
__global__ __launch_bounds__(256) void dist_k(const float* __restrict__ sf,
                                              const float* __restrict__ xn,
                                              float* __restrict__ Ds,
                                              unsigned* __restrict__ h) {
  __shared__ float As[16][68];
  __shared__ float Bs[16][68];
  __shared__ unsigned lh[4096];
  const int tx = threadIdx.x, ty = threadIdx.y;
  const int tid = ty * 16 + tx;
  for (int q = tid; q < 4096; q += 256) lh[q] = 0;
  // triangle block index -> (by,bx), by >= bx
  int b = blockIdx.x;
  int by = (int)((sqrtf(8.f * (float)b + 1.f) - 1.f) * 0.5f);
  while ((by + 1) * (by + 2) / 2 <= b) ++by;
  while (by * (by + 1) / 2 > b) --by;
  int bx = b - by * (by + 1) / 2;
  const int R = by * 64, C = bx * 64;
  float acc[4][4] = {};
  for (int kc = 0; kc < 256; kc += 16) {
    int i = tid >> 2, q = tid & 3;
    float4 va = ((const float4*)(sf + (size_t)(R + i) * 256 + kc))[q];
    As[q * 4 + 0][i] = va.x; As[q * 4 + 1][i] = va.y; As[q * 4 + 2][i] = va.z; As[q * 4 + 3][i] = va.w;
    float4 vb = ((const float4*)(sf + (size_t)(C + i) * 256 + kc))[q];
    Bs[q * 4 + 0][i] = vb.x; Bs[q * 4 + 1][i] = vb.y; Bs[q * 4 + 2][i] = vb.z; Bs[q * 4 + 3][i] = vb.w;
    __syncthreads();
#pragma unroll
    for (int k = 0; k < 16; k++) {
      float4 a = *(const float4*)&As[k][ty * 4];
      float4 b2 = *(const float4*)&Bs[k][tx * 4];
      acc[0][0] += a.x * b2.x; acc[0][1] += a.x * b2.y; acc[0][2] += a.x * b2.z; acc[0][3] += a.x * b2.w;
      acc[1][0] += a.y * b2.x; acc[1][1] += a.y * b2.y; acc[1][2] += a.y * b2.z; acc[1][3] += a.y * b2.w;
      acc[2][0] += a.z * b2.x; acc[2][1] += a.z * b2.y; acc[2][2] += a.z * b2.z; acc[2][3] += a.z * b2.w;
      acc[3][0] += a.w * b2.x; acc[3][1] += a.w * b2.y; acc[3][2] += a.w * b2.z; acc[3][3] += a.w * b2.w;
    }
    __syncthreads();
  }
  int jbase = C + tx * 4;
  float xnj0 = xn[jbase + 0], xnj1 = xn[jbase + 1], xnj2 = xn[jbase + 2], xnj3 = xn[jbase + 3];
#pragma unroll
  for (int r = 0; r < 4; r++) {
    int i = R + ty * 4 + r;
    float xni = xn[i];
    float v[4];
    v[0] = fmaxf(xni + xnj0 - 2.f * acc[r][0], 0.f);
    v[1] = fmaxf(xni + xnj1 - 2.f * acc[r][1], 0.f);
    v[2] = fmaxf(xni + xnj2 - 2.f * acc[r][2], 0.f);
    v[3] = fmaxf(xni + xnj3 - 2.f * acc[r][3], 0.f);
    if (jbase + 3 < i) {
      float4 o; o.x = v[0]; o.y = v[1]; o.z = v[2]; o.w = v[3];
      ((float4*)&Ds[(size_t)i * 2048 + jbase])[0] = o;
      atomicAdd(&lh[__float_as_uint(v[0]) >> 20], 1u);
      atomicAdd(&lh[__float_as_uint(v[1]) >> 20], 1u);
      atomicAdd(&lh[__float_as_uint(v[2]) >> 20], 1u);
      atomicAdd(&lh[__float_as_uint(v[3]) >> 20], 1u);
    } else {
#pragma unroll
      for (int k = 0; k < 4; k++) {
        if (jbase + k < i) {
          Ds[(size_t)i * 2048 + jbase + k] = v[k];
          atomicAdd(&lh[__float_as_uint(v[k]) >> 20], 1u);
        }
      }
    }
  }
  __syncthreads();
  for (int q = tid; q < 4096; q += 256) if (lh[q]) atomicAdd(&h[q], lh[q]);
}

// ---------------- radix-select passes 1/2 (triangle reads) ----------------
__global__ __launch_bounds__(256) void hist1_k(const float* __restrict__ Ds, const unsigned* __restrict__ st,
                                               unsigned* __restrict__ hA, unsigned* __restrict__ hB) {
  __shared__ unsigned lA[4096];
  __shared__ unsigned lB[4096];
  for (int i = threadIdx.x; i < 4096; i += 256) { lA[i] = 0; lB[i] = 0; }
  __syncthreads();
  unsigned s0 = st[0], s1 = st[2];
  int gw = (blockIdx.x * 256 + threadIdx.x) >> 6;
  int lane = threadIdx.x & 63;
  const float* row = Ds + (size_t)gw * 2048;
  for (int j = lane; j < gw; j += 64) {
    unsigned u = __float_as_uint(row[j]);
    unsigned hi = u >> 20, mid = (u >> 8) & 0xFFFu;
    if (hi == s0) atomicAdd(&lA[mid], 1u);
    if (hi == s1) atomicAdd(&lB[mid], 1u);
  }
  __syncthreads();
  for (int i = threadIdx.x; i < 4096; i += 256) {
    if (lA[i]) atomicAdd(&hA[i], lA[i]);
    if (lB[i]) atomicAdd(&hB[i], lB[i]);
  }
}

__global__ __launch_bounds__(256) void hist2_k(const float* __restrict__ Ds, const unsigned* __restrict__ st,
                                               unsigned* __restrict__ hA, unsigned* __restrict__ hB) {
  __shared__ unsigned lA[256];
  __shared__ unsigned lB[256];
  lA[threadIdx.x] = 0; lB[threadIdx.x] = 0;
  __syncthreads();
  unsigned p0 = (st[0] << 12) | st[4];
  unsigned p1 = (st[2] << 12) | st[6];
  int gw = (blockIdx.x * 256 + threadIdx.x) >> 6;
  int lane = threadIdx.x & 63;
  const float* row = Ds + (size_t)gw * 2048;
  for (int j = lane; j < gw; j += 64) {
    unsigned u = __float_as_uint(row[j]);
    unsigned pre = u >> 8;
    if (pre == p0) atomicAdd(&lA[u & 0xFFu], 1u);
    if (pre == p1) atomicAdd(&lB[u & 0xFFu], 1u);
  }
  __syncthreads();
  if (lA[threadIdx.x]) atomicAdd(&hA[threadIdx.x], lA[threadIdx.x]);
  if (lB[threadIdx.x]) atomicAdd(&hB[threadIdx.x], lB[threadIdx.x]);
}

__device__ void scan_find(const unsigned* hist, int nbins, long long k, unsigned* shOut) {
  __shared__ long long tsum[256];
  int per = nbins / 256;
  long long s = 0;
  for (int q = 0; q < per; q++) s += hist[threadIdx.x * per + q];
  tsum[threadIdx.x] = s;
  __syncthreads();
  if (threadIdx.x == 0) {
    long long run = 0;
    for (int t = 0; t < 256; t++) { long long v = tsum[t]; tsum[t] = run; run += v; }
  }
  __syncthreads();
  long long run = tsum[threadIdx.x];
  for (int q = 0; q < per; q++) {
    unsigned c = hist[threadIdx.x * per + q];
    if (k >= run && k < run + (long long)c) { shOut[0] = (unsigned)(threadIdx.x * per + q); shOut[1] = (unsigned)(k - run); }
    run += c;
  }
  __syncthreads();
}

__global__ __launch_bounds__(256) void scan0_k(const unsigned* __restrict__ h, unsigned* __restrict__ st) {
  __shared__ unsigned r0[2];
  __shared__ unsigned r1[2];
  scan_find(h, 4096, K_TRI1, r0);
  scan_find(h, 4096, K_TRI2, r1);
  if (threadIdx.x == 0) { st[0] = r0[0]; st[1] = r0[1]; st[2] = r1[0]; st[3] = r1[1]; }
}

__global__ __launch_bounds__(256) void scan1_k(const unsigned* __restrict__ hA, const unsigned* __restrict__ hB,
                                               unsigned* __restrict__ st) {
  __shared__ unsigned r0[2];
  __shared__ unsigned r1[2];
  long long kA = (long long)st[1];
  long long kB = (long long)st[3];
  scan_find(hA, 4096, kA, r0);
  scan_find(hB, 4096, kB, r1);
  if (threadIdx.x == 0) { st[4] = r0[0]; st[5] = r0[1]; st[6] = r1[0]; st[7] = r1[1]; }
}

__global__ __launch_bounds__(256) void scan2_k(const unsigned* __restrict__ hA, const unsigned* __restrict__ hB,
                                               unsigned* __restrict__ st, float* __restrict__ scal) {
  __shared__ unsigned r0[2];
  __shared__ unsigned r1[2];
  long long kA = (long long)st[5];
  long long kB = (long long)st[7];
  scan_find(hA, 256, kA, r0);
  scan_find(hB, 256, kB, r1);
  if (threadIdx.x == 0) {
    unsigned v1 = (st[0] << 20) | (st[4] << 8) | r0[0];
    unsigned v2 = (st[2] << 20) | (st[6] << 8) | r1[0];
    scal[0] = 0.5f * (__uint_as_float(v1) + __uint_as_float(v2));  // sigma
  }
}

// ---------------- class/domain bucketing (single block) ----------------
__global__ __launch_bounds__(256) void bucket_k(const int* __restrict__ y, const int* __restrict__ l,
                                                int* __restrict__ perm, int* __restrict__ meta,
                                                float* __restrict__ scal) {
  __shared__ unsigned cl[64];
  __shared__ unsigned bs[64];
  __shared__ unsigned cur[64];
  int tid = threadIdx.x;
  if (tid < 64) cl[tid] = 0;
  __syncthreads();
  for (int i = tid; i < N_TOT; i += 256) atomicAdd(&cl[y[i] * 2 + l[i]], 1u);
  __syncthreads();
  if (tid == 0) {
    unsigned run = 0;
    for (int b = 0; b < 62; b++) { bs[b] = run; run += cl[b]; }
    unsigned run2 = 0, cnt0 = 0;
    for (int c = 0; c < NCLASS; c++) {
      int n = (int)(cl[2 * c] + cl[2 * c + 1]);
      meta[c] = n; meta[32 + c] = (int)cl[2 * c]; meta[64 + c] = (int)bs[2 * c];
      meta[96 + c] = (int)run2; run2 += (unsigned)(n * n);
      cnt0 += cl[2 * c];
    }
    scal[1] = (float)((double)cnt0 / (4096.0 * 4096.0));
    scal[2] = (float)((double)(N_TOT - cnt0) / (4096.0 * 4096.0));
  }
  __syncthreads();
  if (tid < 64) cur[tid] = bs[tid];
  __syncthreads();
  for (int i = tid; i < N_TOT; i += 256) {
    int b = y[i] * 2 + l[i];
    unsigned pos = atomicAdd(&cur[b], 1u);
    perm[pos] = i;
  }
}

// ---------------- build per-class K blocks ----------------
__global__ __launch_bounds__(256) void build_k(const float* __restrict__ sf, const float* __restrict__ tf,
                                               const float* __restrict__ xn, const int* __restrict__ perm,
                                               const int* __restrict__ meta, const float* __restrict__ scal,
                                               float* __restrict__ gK) {
  const int c = blockIdx.z;
  const int n = meta[c];
  const int cs = meta[64 + c];
  const int bo = meta[96 + c];
  const int tx = threadIdx.x, ty = threadIdx.y;
  const int i0 = blockIdx.y * 16, j0 = blockIdx.x * 16;
  if (i0 >= n || j0 >= n) return;
  __shared__ float As[16][260];
  __shared__ float Bs[16][260];
  __shared__ int ra[16];
  __shared__ int rb[16];
  int tid = ty * 16 + tx;
  if (tid < 16) { int il = i0 + tid; ra[tid] = (il < n) ? perm[cs + il] : -1; }
  else if (tid < 32) { int jl = j0 + tid - 16; rb[tid - 16] = (jl < n) ? perm[cs + jl] : -1; }
  __syncthreads();
  for (int e = tid; e < 1024; e += 256) {
    int r = e >> 6, q = e & 63;
    int g = ra[r];
    if (g >= 0) {
      const float* src = (g < N_SRC) ? (sf + (size_t)g * DIMF) : (tf + (size_t)(g - N_SRC) * DIMF);
      ((float4*)&As[r][q * 4])[0] = ((const float4*)src)[q];
    }
    int g2 = rb[r];
    if (g2 >= 0) {
      const float* src = (g2 < N_SRC) ? (sf + (size_t)g2 * DIMF) : (tf + (size_t)(g2 - N_SRC) * DIMF);
      ((float4*)&Bs[r][q * 4])[0] = ((const float4*)src)[q];
    }
  }
  __syncthreads();
  int il = i0 + ty, jl = j0 + tx;
  if (il < n && jl < n) {
    float dot = 0.f;
    const float4* a4 = (const float4*)&As[ty][0];
    const float4* b4 = (const float4*)&Bs[tx][0];
#pragma unroll 16
    for (int q = 0; q < 64; q++) {
      float4 a = a4[q], b = b4[q];
      dot += a.x * b.x + a.y * b.y + a.z * b.z + a.w * b.w;
    }
    int gi = ra[ty], gj = rb[tx];
    float d = xn[gi] + xn[gj] - 2.f * dot;
    gK[(size_t)bo + (size_t)il * n + jl] = expf(-d / scal[0]);
  }
}

// ---------------- per-(class,domain) Newton-PCG ----------------
// R6: column matvecs (bc, gradient+Jacobi, CG-q) split across 4 waves with
// LDS partials (256 active threads vs m~66). Otherwise identical to R5:
// bf16 W in LDS (stride 57 dwords, conflict-free), matrix-free Hessian,
// Jacobi-PCG; final term1/term2 recomputed from f32 global K with f32 theta.
__global__ __launch_bounds__(256) void solver_k(const float* __restrict__ gK, const int* __restrict__ meta,
                                                const float* __restrict__ scal, double* __restrict__ acc) {
  const int c = blockIdx.x >> 1, d = blockIdx.x & 1;
  const int n = meta[c];
  const int m0 = meta[32 + c];
  const int m = d ? (n - m0) : m0;
  const int c0 = d ? m0 : 0;
  const int bo = meta[96 + c];
  const float gamma = scal[1 + d];
  const int tid = threadIdx.x;
  const int wv = tid >> 6, lane = tid & 63;

  __shared__ unsigned short Wl[MAXW * WPAD];   // 51072 B
  __shared__ float pS[4 * MAXM];
  __shared__ float pD[4 * MAXM];
  __shared__ float Av[MAXW];
  __shared__ float Sv[MAXW];
  __shared__ float Uv[MAXW];
  __shared__ float Bq[MAXW];    // q (m) then Bv (n) for line search
  __shared__ float bc[MAXM];
  __shared__ float th[MAXM + 1];
  __shared__ float gv[MAXM];
  __shared__ float dgv[MAXM];
  __shared__ float pv[MAXM + 1];
  __shared__ float rv[MAXM + 1];
  __shared__ float zv[MAXM + 1];
  __shared__ float xv[MAXM + 1];
  __shared__ double red[16];

  const float* K = gK + bo;
  const int st = n;
  const int mp2 = (m + 1) & ~1;   // pair-aligned column count
  const int iw0 = (n * wv) >> 2, iw1 = (n * (wv + 1)) >> 2;   // per-wave n-chunk

  // ---- stage W = bf16(K[:, c0:c0+m]), zero the pad column ----
  for (int i = tid >> 2; i < n; i += 64) {
    const float* Kr = K + (size_t)i * st + c0;
    unsigned short* Wr = Wl + i * WPAD;
    for (int j = (tid & 3); j < m; j += 4) {
      unsigned u = __float_as_uint(Kr[j]);
      u += 0x7fffu + ((u >> 16) & 1u);   // RNE to bf16
      Wr[j] = (unsigned short)(u >> 16);
    }
    if ((tid & 3) == 0 && (m & 1)) Wr[m] = 0;
  }
  // ---- bc (exact f32): 4-wave partials over same-domain rows ----
  {
    const int r0 = (m * wv) >> 2, r1 = (m * (wv + 1)) >> 2;
    for (int j = lane; j < m; j += 64) {
      const float* Kr = K + (size_t)(c0 + j) * st + c0;
      float s = 0.f;
      for (int r = r0; r < r1; r++) s += Kr[r];
      pS[wv * MAXM + j] = s;
    }
  }
  __syncthreads();
  for (int j = tid; j < mp2; j += 256) {
    if (j < m) bc[j] = (pS[j] + pS[MAXM + j] + pS[2 * MAXM + j] + pS[3 * MAXM + j]) * (1.0f / 4096.0f);
    th[j] = 0.f;
  }
  __syncthreads();

  for (int it = 0; it < 25; it++) {
    // ---- Av = W th (row matvec, LDS) ----
    for (int i = tid; i < n; i += 256) {
      const unsigned short* Wr = Wl + i * WPAD;
      float a = 0.f;
#pragma unroll 4
      for (int j = 0; j < mp2; j += 2) {
        unsigned u = *(const unsigned*)(Wr + j);
        a += __uint_as_float(u << 16) * th[j]
           + __uint_as_float(u & 0xffff0000u) * th[j + 1];
      }
      Av[i] = a;
    }
    __syncthreads();
    // ---- S, obj ----
    double o = 0.0;
    for (int i = tid; i < n; i += 256) {
      float si = gamma * expf(fminf(Av[i] - 1.f, 30.f));
      Sv[i] = si; o += (double)si;
    }
    for (int j = tid; j < m; j += 256) {
      float t_ = th[j];
      o += (double)(-bc[j] * t_ + LAMBDA * t_ * t_);
    }
    __syncthreads();
    // ---- gradient + Jacobi diag: 4-wave column matvec ----
    for (int j = lane; j < m; j += 64) {
      const unsigned short* Wc = Wl + j;
      float s_ = 0.f, ds_ = 0.f;
      int i = iw0;
      for (; i + 3 < iw1; i += 4) {
        float w0 = bf2f(Wc[(i + 0) * WPAD]), w1 = bf2f(Wc[(i + 1) * WPAD]);
        float w2 = bf2f(Wc[(i + 2) * WPAD]), w3 = bf2f(Wc[(i + 3) * WPAD]);
        float a0 = w0 * Sv[i], a1 = w1 * Sv[i + 1], a2 = w2 * Sv[i + 2], a3 = w3 * Sv[i + 3];
        s_ += a0 + a1 + a2 + a3;
        ds_ += a0 * w0 + a1 * w1 + a2 * w2 + a3 * w3;
      }
      for (; i < iw1; i++) { float w = bf2f(Wc[i * WPAD]); float a = w * Sv[i]; s_ += a; ds_ += a * w; }
      pS[wv * MAXM + j] = s_; pD[wv * MAXM + j] = ds_;
    }
    __syncthreads();
    double gm = 0.0;
    for (int j = tid; j < m; j += 256) {
      float s_ = pS[j] + pS[MAXM + j] + pS[2 * MAXM + j] + pS[3 * MAXM + j];
      float ds_ = pD[j] + pD[MAXM + j] + pD[2 * MAXM + j] + pD[3 * MAXM + j];
      float g = s_ - bc[j] + 2.f * LAMBDA * th[j];
      gv[j] = g;
      dgv[j] = ds_ + 2.f * LAMBDA;
      double ag = fabs((double)g); if (ag > gm) gm = ag;
    }
    double obj, gmax;
    blockReduceSumMax(o, gm, red, obj, gmax);
    if (gmax < 1e-5) break;

    // ---- PCG solve H x = -g (Jacobi precond), x0 = 0 ----
    double rz = 0.0;
    for (int j = tid; j < mp2; j += 256) {
      float r0 = (j < m) ? -gv[j] : 0.f;
      float z0 = (j < m) ? r0 / dgv[j] : 0.f;
      rv[j] = r0; zv[j] = z0; pv[j] = z0; xv[j] = 0.f;
      rz += (double)r0 * (double)z0;
    }
    rz = blockReduceSum(rz, red);
    double rz0 = rz;
    for (int cg = 0; cg < 12; cg++) {
      __syncthreads();  // pv visible
      // u = S .* (W p)
      for (int i = tid; i < n; i += 256) {
        const unsigned short* Wr = Wl + i * WPAD;
        float a = 0.f;
#pragma unroll 4
        for (int j = 0; j < mp2; j += 2) {
          unsigned u = *(const unsigned*)(Wr + j);
          a += __uint_as_float(u << 16) * pv[j]
             + __uint_as_float(u & 0xffff0000u) * pv[j + 1];
        }
        Uv[i] = a * Sv[i];
      }
      __syncthreads();
      // q = W^T u + 2*lambda*p : 4-wave column matvec
      for (int j = lane; j < m; j += 64) {
        const unsigned short* Wc = Wl + j;
        float q = 0.f;
        int i = iw0;
        for (; i + 3 < iw1; i += 4)
          q += bf2f(Wc[(i+0)*WPAD]) * Uv[i]   + bf2f(Wc[(i+1)*WPAD]) * Uv[i+1]
             + bf2f(Wc[(i+2)*WPAD]) * Uv[i+2] + bf2f(Wc[(i+3)*WPAD]) * Uv[i+3];
        for (; i < iw1; i++) q += bf2f(Wc[i * WPAD]) * Uv[i];
        pS[wv * MAXM + j] = q;
      }
      __syncthreads();
      double pq = 0.0;
      for (int j = tid; j < m; j += 256) {
        float q = pS[j] + pS[MAXM + j] + pS[2 * MAXM + j] + pS[3 * MAXM + j] + 2.f * LAMBDA * pv[j];
        Bq[j] = q;
        pq += (double)pv[j] * (double)q;
      }
      pq = blockReduceSum(pq, red);
      if (!(pq > 0.0)) break;
      float alpha = (float)(rz / pq);
      double rznew = 0.0;
      for (int j = tid; j < m; j += 256) {
        xv[j] += alpha * pv[j];
        float rn = rv[j] - alpha * Bq[j];
        rv[j] = rn;
        float zn = rn / dgv[j];
        zv[j] = zn;
        rznew += (double)rn * (double)zn;
      }
      rznew = blockReduceSum(rznew, red);
      if (rznew < 1e-4 * rz0 || cg == 11) break;
      float beta = (float)(rznew / rz);
      for (int j = tid; j < m; j += 256) pv[j] = zv[j] + beta * pv[j];
      rz = rznew;
    }
    __syncthreads();
    // ---- direction d = xv ; gtp ; pmax ----
    double gtpl = 0.0, pml = 0.0;
    for (int j = tid; j < m; j += 256) {
      gtpl += (double)gv[j] * (double)xv[j];
      double ax = fabs((double)xv[j]); if (ax > pml) pml = ax;
    }
    double gtp, pmax;
    blockReduceSumMax(gtpl, pml, red, gtp, pmax);
    if (!(gtp < 0.0)) break;

    float t = 1.f;
    if (-gtp >= 1e-4) {
      // Bv = W d (row matvec) + Armijo
      for (int i = tid; i < n; i += 256) {
        const unsigned short* Wr = Wl + i * WPAD;
        float a = 0.f;
#pragma unroll 4
        for (int j = 0; j < mp2; j += 2) {
          unsigned u = *(const unsigned*)(Wr + j);
          a += __uint_as_float(u << 16) * xv[j]
             + __uint_as_float(u & 0xffff0000u) * xv[j + 1];
        }
        Bq[i] = a;
      }
      __syncthreads();
      for (int ls = 0; ls < 10; ls++) {
        double ol = 0.0;
        for (int i = tid; i < n; i += 256)
          ol += (double)(gamma * expf(fminf(Av[i] + t * Bq[i] - 1.f, 30.f)));
        for (int j = tid; j < m; j += 256) {
          float tj = th[j] + t * xv[j];
          ol += (double)(-bc[j] * tj + LAMBDA * tj * tj);
        }
        double ot = blockReduceSum(ol, red);
        if (ot <= obj + 1e-4 * (double)t * gtp) break;
        t *= 0.5f;
      }
    }
    for (int j = tid; j < mp2; j += 256) th[j] += t * xv[j];
    __syncthreads();
    if ((double)t * pmax < 1e-7) break;
  }

  // ---- final exact f32 evaluation (global K, f32 theta) ----
  __syncthreads();
  for (int i = tid; i < n; i += 256) {
    const float* Kr = K + (size_t)i * st + c0;
    float a = 0.f;
    int j = 0;
    for (; j + 7 < m; j += 8)
      a += th[j] * Kr[j] + th[j+1] * Kr[j+1] + th[j+2] * Kr[j+2] + th[j+3] * Kr[j+3]
         + th[j+4] * Kr[j+4] + th[j+5] * Kr[j+5] + th[j+6] * Kr[j+6] + th[j+7] * Kr[j+7];
    for (; j < m; j++) a += th[j] * Kr[j];
    Av[i] = a;
  }
  __syncthreads();
  double t1l = 0.0, t2l = 0.0;
  for (int i = tid; i < n; i += 256) t2l += (double)(gamma * expf(fminf(Av[i] - 1.f, 30.f)));
  for (int j = tid; j < m; j += 256) t1l += (double)(bc[j] * th[j]);
  double t1 = blockReduceSum(t1l, red);
  double t2 = blockReduceSum(t2l, red);
  if (tid == 0) {
    atomicAdd(&acc[0], t1);
    atomicAdd(&acc[1], t2);
  }
}

__global__ void final_k(const double* __restrict__ acc, float* __restrict__ out) {
  out[0] = (float)(acc[0] - acc[1]);
}

// ---------------- launcher ----------------
extern "C" void kernel_launch(void* const* d_in, const int* in_sizes, int n_in,
                              void* d_out, int out_size, void* d_ws, size_t ws_size,
                              hipStream_t stream) {
  const float* sf = (const float*)d_in[0];
  const float* tf = (const float*)d_in[1];
  const int* y = (const int*)d_in[2];
  const int* l = (const int*)d_in[3];
  char* ws = (char*)d_ws;

  double*   acc    = (double*)(ws + WS_ACC);
  unsigned* hist0  = (unsigned*)(ws + WS_HIST0);
  unsigned* histA  = (unsigned*)(ws + WS_HISTA);
  unsigned* histB  = (unsigned*)(ws + WS_HISTB);
  unsigned* h2A    = (unsigned*)(ws + WS_H2A);
  unsigned* h2B    = (unsigned*)(ws + WS_H2B);
  unsigned* state  = (unsigned*)(ws + WS_STATE);
  int*      meta   = (int*)(ws + WS_META);
  float*    scal   = (float*)(ws + WS_SCAL);
  int*      perm   = (int*)(ws + WS_PERM);
  float*    xnp    = (float*)(ws + WS_XN);
  float*    Ds     = (float*)(ws + WS_DS);
  float*    gK     = (float*)(ws + WS_KBLK);

  hipMemsetAsync(d_ws, 0, ZERO_BYTES, stream);
  hipLaunchKernelGGL(xn_kernel, dim3(1024), dim3(256), 0, stream, sf, tf, xnp);
  hipLaunchKernelGGL(dist_k, dim3(528), dim3(16, 16), 0, stream, sf, xnp, Ds, hist0);
  hipLaunchKernelGGL(scan0_k, dim3(1), dim3(256), 0, stream, hist0, state);
  hipLaunchKernelGGL(hist1_k, dim3(512), dim3(256), 0, stream, Ds, state, histA, histB);
  hipLaunchKernelGGL(scan1_k, dim3(1), dim3(256), 0, stream, histA, histB, state);
  hipLaunchKernelGGL(hist2_k, dim3(512), dim3(256), 0, stream, Ds, state, h2A, h2B);
  hipLaunchKernelGGL(scan2_k, dim3(1), dim3(256), 0, stream, h2A, h2B, state, scal);
  hipLaunchKernelGGL(bucket_k, dim3(1), dim3(256), 0, stream, y, l, perm, meta, scal);
  hipLaunchKernelGGL(build_k, dim3(16, 16, NCLASS), dim3(16, 16), 0, stream, sf, tf, xnp, perm, meta, scal, gK);
  hipLaunchKernelGGL(solver_k, dim3(62), dim3(256), 0, stream, gK, meta, scal, acc);
  hipLaunchKernelGGL(final_k, dim3(1), dim3(1), 0, stream, acc, (float*)d_out);
}